// Round 17
// baseline (295.727 us; speedup 1.0000x reference)
//
#include <hip/hip_runtime.h>
#include <hip/hip_bf16.h>
#include <stdint.h>
#include <math.h>

#define DIM   1024
#define TSEQ  2048
#define BATCH 2
#define NH    16
#define HD    64
#define FFN   4096
#define ROWS  (BATCH*TSEQ)   /* 4096 */
#define QKVN  (3*DIM)        /* 3072 */

typedef __attribute__((ext_vector_type(8))) short s16x8;
typedef __attribute__((ext_vector_type(4))) float f32x4;

__device__ __forceinline__ unsigned short f2bf(float f) {
  union { float f; unsigned u; } v; v.f = f;
  unsigned r = v.u + 0x7fffu + ((v.u >> 16) & 1u);
  return (unsigned short)(r >> 16);
}
__device__ __forceinline__ float bf2f(unsigned short h) {
  union { unsigned u; float f; } v; v.u = ((unsigned)h) << 16; return v.f;
}
__device__ __forceinline__ unsigned pack_bf2(float lo, float hi) {
  union { float f; unsigned u; } a, c; a.f = lo; c.f = hi;
  return (c.u & 0xffff0000u) | (a.u >> 16);
}

__device__ __forceinline__ void gld16(const void* g, void* l) {
  __builtin_amdgcn_global_load_lds((const __attribute__((address_space(1))) void*)g,
                                   (__attribute__((address_space(3))) void*)l, 16, 0, 0);
}

// XCD-aware chunked swizzle (m157, linear): valid when nwg % 8 == 0.
__device__ __forceinline__ int xcd_swz_flat() {
  const int nx = gridDim.x, ny = gridDim.y;
  const int nwg = nx * ny * gridDim.z;
  const int flat = blockIdx.x + nx * (blockIdx.y + ny * blockIdx.z);
  return (flat & 7) * (nwg >> 3) + (flat >> 3);
}

// ---------------------------------------------------------------------------
// Mega weight transpose: ALL 7 weights in one launch. 4096 blocks, 256 thr.
// ---------------------------------------------------------------------------
__global__ void wtrans_all_k(const float* __restrict__ wq, const float* __restrict__ wk,
                             const float* __restrict__ wv, const float* __restrict__ wo,
                             const float* __restrict__ wg, const float* __restrict__ wu,
                             const float* __restrict__ wd,
                             unsigned short* __restrict__ wqkvT, unsigned short* __restrict__ woT,
                             unsigned short* __restrict__ wguT, unsigned short* __restrict__ wdT)
{
  __shared__ unsigned short t[64][65];
  const int id = blockIdx.x;
  const float* w; unsigned short* dst; int K, N, mode, n0, k0;
  if (id < 768) {
    const int z = id >> 8, rem = id & 255;
    w = (z == 0) ? wq : (z == 1) ? wk : wv;
    dst = wqkvT + (size_t)z * 1024 * 1024;
    K = 1024; N = 1024; mode = 0;
    n0 = (rem & 15) * 64; k0 = (rem >> 4) * 64;
  } else if (id < 1024) {
    const int rem = id - 768;
    w = wo; dst = woT; K = 1024; N = 1024; mode = 0;
    n0 = (rem & 15) * 64; k0 = (rem >> 4) * 64;
  } else if (id < 2048) {
    const int rem = id - 1024;
    w = wg; dst = wguT; K = 1024; N = FFN; mode = 1;
    n0 = (rem & 63) * 64; k0 = (rem >> 6) * 64;
  } else if (id < 3072) {
    const int rem = id - 2048;
    w = wu; dst = wguT; K = 1024; N = FFN; mode = 2;
    n0 = (rem & 63) * 64; k0 = (rem >> 6) * 64;
  } else {
    const int rem = id - 3072;
    w = wd; dst = wdT; K = FFN; N = 1024; mode = 0;
    n0 = (rem & 15) * 64; k0 = (rem >> 4) * 64;
  }
  const int tid = threadIdx.x;
  #pragma unroll
  for (int i = 0; i < 16; ++i) {
    const int r = i*4 + (tid >> 6), c = tid & 63;
    t[r][c] = f2bf(w[(size_t)(k0 + r) * N + n0 + c]);
  }
  __syncthreads();
  #pragma unroll
  for (int i = 0; i < 16; ++i) {
    const int r = i*4 + (tid >> 6), c = tid & 63;
    const int n = n0 + r;
    int dr = n;
    if (mode == 1) dr = ((n >> 4) << 5) + (n & 15);
    if (mode == 2) dr = ((n >> 4) << 5) + 16 + (n & 15);
    dst[(size_t)dr * K + k0 + c] = t[c][r];
  }
}

// ---------------------------------------------------------------------------
// V transpose: qkv [ROWS][3072] (v at col 2048) -> vt [32 bh][64 d][2048 t]
// ---------------------------------------------------------------------------
__global__ void vtrans_k(const unsigned short* __restrict__ qkv, unsigned short* __restrict__ vt)
{
  __shared__ unsigned short t[64][65];
  const int tt0 = blockIdx.x * 64;
  const int bh = blockIdx.y, b = bh >> 4, h = bh & 15;
  const int tid = threadIdx.x;
  const unsigned short* src = qkv + (size_t)(b*TSEQ + tt0) * QKVN + 2*DIM + h*HD;
  #pragma unroll
  for (int i = 0; i < 16; ++i) {
    const int r = i*4 + (tid >> 6), c = tid & 63;
    t[r][c] = src[(size_t)r * QKVN + c];
  }
  __syncthreads();
  unsigned short* dst = vt + (size_t)bh * HD * TSEQ + tt0;
  #pragma unroll
  for (int i = 0; i < 16; ++i) {
    const int d = i*4 + (tid >> 6), c = tid & 63;
    dst[(size_t)d * TSEQ + c] = t[c][d];
  }
}

// ---------------------------------------------------------------------------
// RMSNorm: x [ROWS][DIM] fp32 -> out bf16. grid ROWS, block 256.
// ---------------------------------------------------------------------------
__global__ void rmsnorm_k(const float* __restrict__ x, const float* __restrict__ w,
                          unsigned short* __restrict__ o)
{
  const int row = blockIdx.x, tid = threadIdx.x;
  const float4 v = ((const float4*)(x + (size_t)row * DIM))[tid];
  float ss = v.x*v.x + v.y*v.y + v.z*v.z + v.w*v.w;
  #pragma unroll
  for (int off = 32; off >= 1; off >>= 1) ss += __shfl_xor(ss, off);
  __shared__ float sred[4];
  if ((tid & 63) == 0) sred[tid >> 6] = ss;
  __syncthreads();
  const float tot = sred[0] + sred[1] + sred[2] + sred[3];
  const float r = rsqrtf(tot * (1.0f/DIM) + 1e-6f);
  const float4 wv = ((const float4*)w)[tid];
  ushort4 ov;
  ov.x = f2bf(v.x*r*wv.x); ov.y = f2bf(v.y*r*wv.y);
  ov.z = f2bf(v.z*r*wv.z); ov.w = f2bf(v.w*r*wv.w);
  ((ushort4*)(o + (size_t)row * DIM))[tid] = ov;
}

// ---------------------------------------------------------------------------
// RMSNorm3: x1 = x + p0 + p1 (bf16 partials); xn = rmsnorm(x1)*w (bf16).
// ---------------------------------------------------------------------------
__global__ void rmsnorm3_k(const float* __restrict__ x, const unsigned short* __restrict__ p0,
                           const unsigned short* __restrict__ p1, const float* __restrict__ w,
                           float* __restrict__ x1, unsigned short* __restrict__ o)
{
  const int row = blockIdx.x, tid = threadIdx.x;
  const size_t base = (size_t)row * DIM;
  const float4 a = ((const float4*)(x + base))[tid];
  const ushort4 b = ((const ushort4*)(p0 + base))[tid];
  const ushort4 c = ((const ushort4*)(p1 + base))[tid];
  float4 v;
  v.x = a.x + bf2f(b.x) + bf2f(c.x); v.y = a.y + bf2f(b.y) + bf2f(c.y);
  v.z = a.z + bf2f(b.z) + bf2f(c.z); v.w = a.w + bf2f(b.w) + bf2f(c.w);
  ((float4*)(x1 + base))[tid] = v;
  float ss = v.x*v.x + v.y*v.y + v.z*v.z + v.w*v.w;
  #pragma unroll
  for (int off = 32; off >= 1; off >>= 1) ss += __shfl_xor(ss, off);
  __shared__ float sred[4];
  if ((tid & 63) == 0) sred[tid >> 6] = ss;
  __syncthreads();
  const float tot = sred[0] + sred[1] + sred[2] + sred[3];
  const float r = rsqrtf(tot * (1.0f/DIM) + 1e-6f);
  const float4 wv = ((const float4*)w)[tid];
  ushort4 ov;
  ov.x = f2bf(v.x*r*wv.x); ov.y = f2bf(v.y*r*wv.y);
  ov.z = f2bf(v.z*r*wv.z); ov.w = f2bf(v.w*r*wv.w);
  ((ushort4*)(o + base))[tid] = ov;
}

// ---------------------------------------------------------------------------
// Final reduce: out = x1 + q0+q1+q2+q3 (bf16 partials). grid 4096, block 256.
// ---------------------------------------------------------------------------
__global__ void resadd5_k(const float* __restrict__ x1,
                          const unsigned short* __restrict__ q0, const unsigned short* __restrict__ q1,
                          const unsigned short* __restrict__ q2, const unsigned short* __restrict__ q3,
                          float* __restrict__ o)
{
  const size_t i = (size_t)blockIdx.x * 256 + threadIdx.x;
  const float4 a = ((const float4*)x1)[i];
  const ushort4 b = ((const ushort4*)q0)[i];
  const ushort4 c = ((const ushort4*)q1)[i];
  const ushort4 d = ((const ushort4*)q2)[i];
  const ushort4 e = ((const ushort4*)q3)[i];
  float4 v;
  v.x = a.x + bf2f(b.x) + bf2f(c.x) + bf2f(d.x) + bf2f(e.x);
  v.y = a.y + bf2f(b.y) + bf2f(c.y) + bf2f(d.y) + bf2f(e.y);
  v.z = a.z + bf2f(b.z) + bf2f(c.z) + bf2f(d.z) + bf2f(e.z);
  v.w = a.w + bf2f(b.w) + bf2f(c.w) + bf2f(d.w) + bf2f(e.w);
  ((float4*)o)[i] = v;
}

// ---------------------------------------------------------------------------
// GEMM 128x128 split-K (m97 structure + XCD swizzle). grid (N/128, M/128, NS).
// NS=1, EPI=0: direct bf16 store (Ksp = K).
// NS>1, EPI=0: bf16 partial to P + bz*M*ldc.
// NS=1, EPI=1: silu(gate)*up pair store. Interleaved wguT (16g/16u per 32):
//   wave tile = 64 interleaved cols at n0+wc; pairs (acc[i][0],acc[i][1]) ->
//   h col (n0+wc)/2 + ec, (acc[i][2],acc[i][3]) -> +16. ldc = FFN (h cols).
// ---------------------------------------------------------------------------
template<int NS, int EPI>
__global__ void gemm128sp(const unsigned short* __restrict__ A, int lda,
                          const unsigned short* __restrict__ BT, int ldb,
                          unsigned short* __restrict__ P, int ldc, int Ksp)
{
  __shared__ __align__(16) unsigned short lA[128*64];
  __shared__ __align__(16) unsigned short lB[128*64];
  const int nx = gridDim.x, ny = gridDim.y;
  const int w = xcd_swz_flat();
  const int bx = w % nx, by = (w / nx) % ny, bz = w / (nx * ny);
  const int tid = threadIdx.x;
  const int lane = tid & 63;
  const int wid = tid >> 6;
  const int m0 = by * 128, n0 = bx * 128;
  const int Koff = bz * Ksp;
  P += (size_t)bz * ((size_t)ny * 128) * ldc;
  const int wr = (wid >> 1) * 64, wc = (wid & 1) * 64;
  const int lrow = lane & 15, lk8 = (lane >> 4) * 8;

  f32x4 acc[4][4] = {};

  for (int k0 = Koff; k0 < Koff + Ksp; k0 += 64) {
    #pragma unroll
    for (int c = 0; c < 4; ++c) {
      const int boff = c*4096 + tid*16;
      const int row = boff >> 7, colb = boff & 127;
      gld16((const char*)A + ((size_t)(m0+row)*lda + k0)*2 + colb, (char*)lA + boff);
    }
    #pragma unroll
    for (int c = 0; c < 4; ++c) {
      const int boff = c*4096 + tid*16;
      const int row = boff >> 7, colb = boff & 127;
      gld16((const char*)BT + ((size_t)(n0+row)*ldb + k0)*2 + colb, (char*)lB + boff);
    }
    __syncthreads();
    #pragma unroll
    for (int kk = 0; kk < 64; kk += 32) {
      s16x8 af[4], bf[4];
      #pragma unroll
      for (int i = 0; i < 4; ++i) af[i] = *(const s16x8*)&lA[(wr + i*16 + lrow)*64 + kk + lk8];
      #pragma unroll
      for (int j = 0; j < 4; ++j) bf[j] = *(const s16x8*)&lB[(wc + j*16 + lrow)*64 + kk + lk8];
      #pragma unroll
      for (int i = 0; i < 4; ++i)
        #pragma unroll
        for (int j = 0; j < 4; ++j)
          acc[i][j] = __builtin_amdgcn_mfma_f32_16x16x32_bf16(af[i], bf[j], acc[i][j], 0, 0, 0);
    }
    __syncthreads();
  }
  const int er = (lane >> 4) * 4, ec = lane & 15;
  if (EPI == 0) {
    #pragma unroll
    for (int i = 0; i < 4; ++i)
      #pragma unroll
      for (int j = 0; j < 4; ++j) {
        const int gr = m0 + wr + i*16 + er;
        const int gc = n0 + wc + j*16 + ec;
        #pragma unroll
        for (int e = 0; e < 4; ++e)
          P[(size_t)(gr + e) * ldc + gc] = f2bf(acc[i][j][e]);
      }
  } else {
    #pragma unroll
    for (int i = 0; i < 4; ++i)
      #pragma unroll
      for (int tp = 0; tp < 2; ++tp) {
        const int gr = m0 + wr + i*16 + er;
        const int hc = ((n0 + wc) >> 1) + tp*16 + ec;
        #pragma unroll
        for (int e = 0; e < 4; ++e) {
          const float gv = acc[i][2*tp][e];
          const float uv = acc[i][2*tp + 1][e];
          const float hv = gv / (1.f + __expf(-gv)) * uv;
          P[(size_t)(gr + e) * ldc + hc] = f2bf(hv);
        }
      }
  }
}

// ---------------------------------------------------------------------------
// Flash attention (causal), KVBLK=128. grid (T/128, B*H), block 512.
// ---------------------------------------------------------------------------
__global__ __launch_bounds__(512) void attn_fwd(const unsigned short* __restrict__ qkv,
                                                const unsigned short* __restrict__ vt,
                                                unsigned short* __restrict__ outp)
{
  __shared__ __align__(16) unsigned short lK[2][128*64];
  __shared__ __align__(16) unsigned short lV[2][64*128];
  const int nx = gridDim.x;
  const int wsz = xcd_swz_flat();
  const int qblk = wsz % nx;
  const int bh = wsz / nx, b = bh >> 4, h = bh & 15;
  const int tid = threadIdx.x, wid = tid >> 6, lane = tid & 63;
  const int lq = lane & 15, g = lane >> 4;

  const int qrow = qblk*128 + wid*16;
  const int myq = qrow + lq;

  const size_t qbase = ((size_t)(b*TSEQ + myq)) * QKVN + h*HD;
  const s16x8 qf0 = *(const s16x8*)&qkv[qbase + g*8];
  const s16x8 qf1 = *(const s16x8*)&qkv[qbase + 32 + g*8];

  const int pk = tid * 16;
  const int Lk0 = pk ^ (((pk >> 7) & 7) << 4);
  const int Lk1 = (pk + 8192) ^ ((((pk + 8192) >> 7) & 7) << 4);
  const char* ks0 = (const char*)qkv + (((size_t)(b*TSEQ + (Lk0 >> 7))) * QKVN + DIM + h*HD) * 2 + (Lk0 & 127);
  const char* ks1 = (const char*)qkv + (((size_t)(b*TSEQ + (Lk1 >> 7))) * QKVN + DIM + h*HD) * 2 + (Lk1 & 127);
  const int Lv0 = pk ^ (((pk >> 8) & 7) << 4);
  const int Lv1 = (pk + 8192) ^ ((((pk + 8192) >> 8) & 7) << 4);
  const char* vs0 = (const char*)vt + (((size_t)bh*HD + (Lv0 >> 8)) * TSEQ) * 2 + (Lv0 & 255);
  const char* vs1 = (const char*)vt + (((size_t)bh*HD + (Lv1 >> 8)) * TSEQ) * 2 + (Lv1 & 255);

#define STAGE_KV(kt, buf) do { \
    gld16(ks0 + (size_t)(kt)*128*(QKVN*2), (char*)lK[buf] + pk); \
    gld16(ks1 + (size_t)(kt)*128*(QKVN*2), (char*)lK[buf] + pk + 8192); \
    gld16(vs0 + (size_t)(kt)*256,          (char*)lV[buf] + pk); \
    gld16(vs1 + (size_t)(kt)*256,          (char*)lV[buf] + pk + 8192); } while (0)

  float mrun = -INFINITY, lrun = 0.f;
  f32x4 of[4] = {};

  const int nkt = qblk + 1;

  STAGE_KV(0, 0);
  int cur = 0;

  for (int kt = 0; kt < nkt; ++kt) {
    __syncthreads();
    if (kt + 1 < nkt) STAGE_KV(kt + 1, cur ^ 1);
    {
      const char* Kb = (const char*)lK[cur];
      const char* Vb = (const char*)lV[cur];
      f32x4 sacc[8];
      __builtin_amdgcn_s_setprio(1);
      #pragma unroll
      for (int s = 0; s < 8; ++s) {
        const int r = s*16 + lq;
        const int sw = (r & 7) << 4;
        const s16x8 kf0 = *(const s16x8*)(Kb + r*128 + ((g*16) ^ sw));
        const s16x8 kf1 = *(const s16x8*)(Kb + r*128 + ((64 + g*16) ^ sw));
        f32x4 z = {0.f,0.f,0.f,0.f};
        z = __builtin_amdgcn_mfma_f32_16x16x32_bf16(kf0, qf0, z, 0,0,0);
        z = __builtin_amdgcn_mfma_f32_16x16x32_bf16(kf1, qf1, z, 0,0,0);
        sacc[s] = z;
      }
      __builtin_amdgcn_s_setprio(0);
      float p[8][4];
      float mt = -INFINITY;
      #pragma unroll
      for (int s = 0; s < 8; ++s)
        #pragma unroll
        for (int e = 0; e < 4; ++e) {
          const int key = kt*128 + s*16 + 4*g + e;
          const float v = (key <= myq) ? sacc[s][e]*0.125f : -INFINITY;
          p[s][e] = v;
          mt = fmaxf(mt, v);
        }
      mt = fmaxf(mt, __shfl_xor(mt, 16));
      mt = fmaxf(mt, __shfl_xor(mt, 32));
      const float mnew = fmaxf(mrun, mt);
      const float scale = __expf(mrun - mnew);
      float ssum = 0.f;
      #pragma unroll
      for (int s = 0; s < 8; ++s)
        #pragma unroll
        for (int e = 0; e < 4; ++e) {
          p[s][e] = __expf(p[s][e] - mnew);
          ssum += p[s][e];
        }
      ssum += __shfl_xor(ssum, 16);
      ssum += __shfl_xor(ssum, 32);
      lrun = lrun * scale + ssum;
      mrun = mnew;
      #pragma unroll
      for (int d0b = 0; d0b < 4; ++d0b) of[d0b] = of[d0b] * scale;
      #pragma unroll
      for (int hh = 0; hh < 4; ++hh) {
        unsigned w[4];
        #pragma unroll
        for (int j = 0; j < 4; ++j) w[j] = pack_bf2(p[2*hh][j], p[2*hh+1][j]);
        s16x8 bp;
        #pragma unroll
        for (int e = 0; e < 8; ++e) {
          const int srcg = 2*(g & 1) + (e >> 2);
          const unsigned ww = (unsigned)__shfl((int)w[e & 3], lq | (srcg << 4));
          bp[e] = (short)((g >= 2) ? (ww >> 16) : (ww & 0xffffu));
        }
        __builtin_amdgcn_s_setprio(1);
        #pragma unroll
        for (int d0b = 0; d0b < 4; ++d0b) {
          const int r = d0b*16 + lq;
          const int sw = (r & 7) << 4;
          const s16x8 vf = *(const s16x8*)(Vb + r*256 + ((hh*64 + g*16) ^ sw));
          of[d0b] = __builtin_amdgcn_mfma_f32_16x16x32_bf16(vf, bp, of[d0b], 0,0,0);
        }
        __builtin_amdgcn_s_setprio(0);
      }
    }
    cur ^= 1;
  }
  const float inv = 1.f / lrun;
  const size_t obase = ((size_t)(b*TSEQ + myq)) * DIM + h*HD;
  #pragma unroll
  for (int d0b = 0; d0b < 4; ++d0b) {
    ushort4 o;
    o.x = f2bf(of[d0b][0] * inv);
    o.y = f2bf(of[d0b][1] * inv);
    o.z = f2bf(of[d0b][2] * inv);
    o.w = f2bf(of[d0b][3] * inv);
    *(ushort4*)&outp[obase + d0b*16 + 4*g] = o;
  }
#undef STAGE_KV
}

// ---------------------------------------------------------------------------
extern "C" void kernel_launch(void* const* d_in, const int* in_sizes, int n_in,
                              void* d_out, int out_size, void* d_ws, size_t ws_size,
                              hipStream_t stream)
{
  const float* x   = (const float*)d_in[0];
  const float* wq  = (const float*)d_in[1];
  const float* wk  = (const float*)d_in[2];
  const float* wv  = (const float*)d_in[3];
  const float* wo  = (const float*)d_in[4];
  const float* wg  = (const float*)d_in[5];
  const float* wu  = (const float*)d_in[6];
  const float* wd  = (const float*)d_in[7];
  const float* anw = (const float*)d_in[8];
  const float* fnw = (const float*)d_in[9];
  float* outp = (float*)d_out;

  const size_t MB = 1024*1024;
  const size_t RD = (size_t)ROWS * DIM;
  char* ws = (char*)d_ws;
  float*          x1    = (float*)         (ws + 0);
  unsigned short* wdT   = (unsigned short*)(ws + 16*MB);
  unsigned short* wguT  = (unsigned short*)(ws + 24*MB);
  unsigned short* wqkvT = (unsigned short*)(ws + 40*MB);
  unsigned short* woT   = (unsigned short*)(ws + 46*MB);
  unsigned short* xn    = (unsigned short*)(ws + 48*MB);
  unsigned short* qkv   = (unsigned short*)(ws + 56*MB);
  unsigned short* vtb   = (unsigned short*)(ws + 80*MB);
  unsigned short* aout  = (unsigned short*)(ws + 88*MB);
  unsigned short* pwo   = (unsigned short*)(ws + 56*MB);   // 2 x 8MB bf16 WO partials
  unsigned short* hbuf  = (unsigned short*)(ws + 56*MB);   // 32MB
  unsigned short* pdn   = (unsigned short*)(ws + 24*MB);   // 4 x 8MB bf16 down partials

  const dim3 blk(256);

  // all weight transposes in one launch
  wtrans_all_k<<<dim3(4096), blk, 0, stream>>>(wq, wk, wv, wo, wg, wu, wd,
                                               wqkvT, woT, wguT, wdT);

  // attention path
  rmsnorm_k<<<ROWS, blk, 0, stream>>>(x, anw, xn);
  gemm128sp<1,0><<<dim3(QKVN/128, ROWS/128, 1), blk, 0, stream>>>(xn, DIM, wqkvT, DIM, qkv, QKVN, DIM);
  vtrans_k<<<dim3(TSEQ/64, BATCH*NH), blk, 0, stream>>>(qkv, vtb);
  attn_fwd<<<dim3(TSEQ/128, BATCH*NH), dim3(512), 0, stream>>>(qkv, vtb, aout);
  gemm128sp<2,0><<<dim3(DIM/128, ROWS/128, 2), blk, 0, stream>>>(aout, DIM, woT, DIM, pwo, DIM, DIM/2);
  rmsnorm3_k<<<ROWS, blk, 0, stream>>>(x, pwo, pwo + RD, fnw, x1, xn);

  // ffn path: gate/up on the m97 structure with fused silu epilogue
  gemm128sp<1,1><<<dim3(2*FFN/128, ROWS/128, 1), blk, 0, stream>>>(xn, DIM, wguT, DIM, hbuf, FFN, DIM);
  gemm128sp<4,0><<<dim3(DIM/128, ROWS/128, 4), blk, 0, stream>>>(hbuf, FFN, wdT, FFN, pdn, DIM, FFN/4);
  resadd5_k<<<dim3(ROWS*DIM/1024), blk, 0, stream>>>(x1, pdn, pdn + RD, pdn + 2*RD, pdn + 3*RD, outp);
}

// Round 18
// 286.122 us; speedup vs baseline: 1.0336x; 1.0336x over previous
//
#include <hip/hip_runtime.h>
#include <hip/hip_bf16.h>
#include <stdint.h>
#include <math.h>

#define DIM   1024
#define TSEQ  2048
#define BATCH 2
#define NH    16
#define HD    64
#define FFN   4096
#define ROWS  (BATCH*TSEQ)   /* 4096 */
#define QKVN  (3*DIM)        /* 3072 */

typedef __attribute__((ext_vector_type(8))) short s16x8;
typedef __attribute__((ext_vector_type(4))) float f32x4;

__device__ __forceinline__ unsigned short f2bf(float f) {
  union { float f; unsigned u; } v; v.f = f;
  unsigned r = v.u + 0x7fffu + ((v.u >> 16) & 1u);
  return (unsigned short)(r >> 16);
}
__device__ __forceinline__ float bf2f(unsigned short h) {
  union { unsigned u; float f; } v; v.u = ((unsigned)h) << 16; return v.f;
}
__device__ __forceinline__ unsigned pack_bf2(float lo, float hi) {
  union { float f; unsigned u; } a, c; a.f = lo; c.f = hi;
  return (c.u & 0xffff0000u) | (a.u >> 16);
}

__device__ __forceinline__ void gld16(const void* g, void* l) {
  __builtin_amdgcn_global_load_lds((const __attribute__((address_space(1))) void*)g,
                                   (__attribute__((address_space(3))) void*)l, 16, 0, 0);
}

// XCD-aware chunked swizzle (m157, linear): valid when nwg % 8 == 0.
__device__ __forceinline__ int xcd_swz_flat() {
  const int nx = gridDim.x, ny = gridDim.y;
  const int nwg = nx * ny * gridDim.z;
  const int flat = blockIdx.x + nx * (blockIdx.y + ny * blockIdx.z);
  return (flat & 7) * (nwg >> 3) + (flat >> 3);
}

// ---------------------------------------------------------------------------
// Mega weight transpose: ALL 7 weights in one launch. 4096 blocks, 256 thr.
// ---------------------------------------------------------------------------
__global__ void wtrans_all_k(const float* __restrict__ wq, const float* __restrict__ wk,
                             const float* __restrict__ wv, const float* __restrict__ wo,
                             const float* __restrict__ wg, const float* __restrict__ wu,
                             const float* __restrict__ wd,
                             unsigned short* __restrict__ wqkvT, unsigned short* __restrict__ woT,
                             unsigned short* __restrict__ wguT, unsigned short* __restrict__ wdT)
{
  __shared__ unsigned short t[64][65];
  const int id = blockIdx.x;
  const float* w; unsigned short* dst; int K, N, mode, n0, k0;
  if (id < 768) {
    const int z = id >> 8, rem = id & 255;
    w = (z == 0) ? wq : (z == 1) ? wk : wv;
    dst = wqkvT + (size_t)z * 1024 * 1024;
    K = 1024; N = 1024; mode = 0;
    n0 = (rem & 15) * 64; k0 = (rem >> 4) * 64;
  } else if (id < 1024) {
    const int rem = id - 768;
    w = wo; dst = woT; K = 1024; N = 1024; mode = 0;
    n0 = (rem & 15) * 64; k0 = (rem >> 4) * 64;
  } else if (id < 2048) {
    const int rem = id - 1024;
    w = wg; dst = wguT; K = 1024; N = FFN; mode = 1;
    n0 = (rem & 63) * 64; k0 = (rem >> 6) * 64;
  } else if (id < 3072) {
    const int rem = id - 2048;
    w = wu; dst = wguT; K = 1024; N = FFN; mode = 2;
    n0 = (rem & 63) * 64; k0 = (rem >> 6) * 64;
  } else {
    const int rem = id - 3072;
    w = wd; dst = wdT; K = FFN; N = 1024; mode = 0;
    n0 = (rem & 15) * 64; k0 = (rem >> 4) * 64;
  }
  const int tid = threadIdx.x;
  #pragma unroll
  for (int i = 0; i < 16; ++i) {
    const int r = i*4 + (tid >> 6), c = tid & 63;
    t[r][c] = f2bf(w[(size_t)(k0 + r) * N + n0 + c]);
  }
  __syncthreads();
  #pragma unroll
  for (int i = 0; i < 16; ++i) {
    const int r = i*4 + (tid >> 6), c = tid & 63;
    const int n = n0 + r;
    int dr = n;
    if (mode == 1) dr = ((n >> 4) << 5) + (n & 15);
    if (mode == 2) dr = ((n >> 4) << 5) + 16 + (n & 15);
    dst[(size_t)dr * K + k0 + c] = t[c][r];
  }
}

// ---------------------------------------------------------------------------
// V transpose: qkv [ROWS][3072] (v at col 2048) -> vt [32 bh][64 d][2048 t]
// ---------------------------------------------------------------------------
__global__ void vtrans_k(const unsigned short* __restrict__ qkv, unsigned short* __restrict__ vt)
{
  __shared__ unsigned short t[64][65];
  const int tt0 = blockIdx.x * 64;
  const int bh = blockIdx.y, b = bh >> 4, h = bh & 15;
  const int tid = threadIdx.x;
  const unsigned short* src = qkv + (size_t)(b*TSEQ + tt0) * QKVN + 2*DIM + h*HD;
  #pragma unroll
  for (int i = 0; i < 16; ++i) {
    const int r = i*4 + (tid >> 6), c = tid & 63;
    t[r][c] = src[(size_t)r * QKVN + c];
  }
  __syncthreads();
  unsigned short* dst = vt + (size_t)bh * HD * TSEQ + tt0;
  #pragma unroll
  for (int i = 0; i < 16; ++i) {
    const int d = i*4 + (tid >> 6), c = tid & 63;
    dst[(size_t)d * TSEQ + c] = t[c][d];
  }
}

// ---------------------------------------------------------------------------
// RMSNorm: x [ROWS][DIM] fp32 -> out bf16. grid ROWS, block 256.
// ---------------------------------------------------------------------------
__global__ void rmsnorm_k(const float* __restrict__ x, const float* __restrict__ w,
                          unsigned short* __restrict__ o)
{
  const int row = blockIdx.x, tid = threadIdx.x;
  const float4 v = ((const float4*)(x + (size_t)row * DIM))[tid];
  float ss = v.x*v.x + v.y*v.y + v.z*v.z + v.w*v.w;
  #pragma unroll
  for (int off = 32; off >= 1; off >>= 1) ss += __shfl_xor(ss, off);
  __shared__ float sred[4];
  if ((tid & 63) == 0) sred[tid >> 6] = ss;
  __syncthreads();
  const float tot = sred[0] + sred[1] + sred[2] + sred[3];
  const float r = rsqrtf(tot * (1.0f/DIM) + 1e-6f);
  const float4 wv = ((const float4*)w)[tid];
  ushort4 ov;
  ov.x = f2bf(v.x*r*wv.x); ov.y = f2bf(v.y*r*wv.y);
  ov.z = f2bf(v.z*r*wv.z); ov.w = f2bf(v.w*r*wv.w);
  ((ushort4*)(o + (size_t)row * DIM))[tid] = ov;
}

// ---------------------------------------------------------------------------
// RMSNorm3: x1 = x + p0 + p1 (bf16 partials); xn = rmsnorm(x1)*w (bf16).
// ---------------------------------------------------------------------------
__global__ void rmsnorm3_k(const float* __restrict__ x, const unsigned short* __restrict__ p0,
                           const unsigned short* __restrict__ p1, const float* __restrict__ w,
                           float* __restrict__ x1, unsigned short* __restrict__ o)
{
  const int row = blockIdx.x, tid = threadIdx.x;
  const size_t base = (size_t)row * DIM;
  const float4 a = ((const float4*)(x + base))[tid];
  const ushort4 b = ((const ushort4*)(p0 + base))[tid];
  const ushort4 c = ((const ushort4*)(p1 + base))[tid];
  float4 v;
  v.x = a.x + bf2f(b.x) + bf2f(c.x); v.y = a.y + bf2f(b.y) + bf2f(c.y);
  v.z = a.z + bf2f(b.z) + bf2f(c.z); v.w = a.w + bf2f(b.w) + bf2f(c.w);
  ((float4*)(x1 + base))[tid] = v;
  float ss = v.x*v.x + v.y*v.y + v.z*v.z + v.w*v.w;
  #pragma unroll
  for (int off = 32; off >= 1; off >>= 1) ss += __shfl_xor(ss, off);
  __shared__ float sred[4];
  if ((tid & 63) == 0) sred[tid >> 6] = ss;
  __syncthreads();
  const float tot = sred[0] + sred[1] + sred[2] + sred[3];
  const float r = rsqrtf(tot * (1.0f/DIM) + 1e-6f);
  const float4 wv = ((const float4*)w)[tid];
  ushort4 ov;
  ov.x = f2bf(v.x*r*wv.x); ov.y = f2bf(v.y*r*wv.y);
  ov.z = f2bf(v.z*r*wv.z); ov.w = f2bf(v.w*r*wv.w);
  ((ushort4*)(o + base))[tid] = ov;
}

// ---------------------------------------------------------------------------
// Final reduce: out = x1 + q0+q1+q2+q3 (bf16 partials). grid 4096, block 256.
// ---------------------------------------------------------------------------
__global__ void resadd5_k(const float* __restrict__ x1,
                          const unsigned short* __restrict__ q0, const unsigned short* __restrict__ q1,
                          const unsigned short* __restrict__ q2, const unsigned short* __restrict__ q3,
                          float* __restrict__ o)
{
  const size_t i = (size_t)blockIdx.x * 256 + threadIdx.x;
  const float4 a = ((const float4*)x1)[i];
  const ushort4 b = ((const ushort4*)q0)[i];
  const ushort4 c = ((const ushort4*)q1)[i];
  const ushort4 d = ((const ushort4*)q2)[i];
  const ushort4 e = ((const ushort4*)q3)[i];
  float4 v;
  v.x = a.x + bf2f(b.x) + bf2f(c.x) + bf2f(d.x) + bf2f(e.x);
  v.y = a.y + bf2f(b.y) + bf2f(c.y) + bf2f(d.y) + bf2f(e.y);
  v.z = a.z + bf2f(b.z) + bf2f(c.z) + bf2f(d.z) + bf2f(e.z);
  v.w = a.w + bf2f(b.w) + bf2f(c.w) + bf2f(d.w) + bf2f(e.w);
  ((float4*)o)[i] = v;
}

// ---------------------------------------------------------------------------
// GEMM 128x128 split-K (m97 structure + XCD swizzle). grid (N/128, M/128, NS).
// NS=1: direct bf16 output (P = C, Ksp = K).
// ---------------------------------------------------------------------------
template<int NS>
__global__ void gemm128sp(const unsigned short* __restrict__ A, int lda,
                          const unsigned short* __restrict__ BT, int ldb,
                          unsigned short* __restrict__ P, int ldc, int Ksp)
{
  __shared__ __align__(16) unsigned short lA[128*64];
  __shared__ __align__(16) unsigned short lB[128*64];
  const int nx = gridDim.x, ny = gridDim.y;
  const int w = xcd_swz_flat();
  const int bx = w % nx, by = (w / nx) % ny, bz = w / (nx * ny);
  const int tid = threadIdx.x;
  const int lane = tid & 63;
  const int wid = tid >> 6;
  const int m0 = by * 128, n0 = bx * 128;
  const int Koff = bz * Ksp;
  P += (size_t)bz * ((size_t)ny * 128) * ldc;
  const int wr = (wid >> 1) * 64, wc = (wid & 1) * 64;
  const int lrow = lane & 15, lk8 = (lane >> 4) * 8;

  f32x4 acc[4][4] = {};

  for (int k0 = Koff; k0 < Koff + Ksp; k0 += 64) {
    #pragma unroll
    for (int c = 0; c < 4; ++c) {
      const int boff = c*4096 + tid*16;
      const int row = boff >> 7, colb = boff & 127;
      gld16((const char*)A + ((size_t)(m0+row)*lda + k0)*2 + colb, (char*)lA + boff);
    }
    #pragma unroll
    for (int c = 0; c < 4; ++c) {
      const int boff = c*4096 + tid*16;
      const int row = boff >> 7, colb = boff & 127;
      gld16((const char*)BT + ((size_t)(n0+row)*ldb + k0)*2 + colb, (char*)lB + boff);
    }
    __syncthreads();
    #pragma unroll
    for (int kk = 0; kk < 64; kk += 32) {
      s16x8 af[4], bf[4];
      #pragma unroll
      for (int i = 0; i < 4; ++i) af[i] = *(const s16x8*)&lA[(wr + i*16 + lrow)*64 + kk + lk8];
      #pragma unroll
      for (int j = 0; j < 4; ++j) bf[j] = *(const s16x8*)&lB[(wc + j*16 + lrow)*64 + kk + lk8];
      #pragma unroll
      for (int i = 0; i < 4; ++i)
        #pragma unroll
        for (int j = 0; j < 4; ++j)
          acc[i][j] = __builtin_amdgcn_mfma_f32_16x16x32_bf16(af[i], bf[j], acc[i][j], 0, 0, 0);
    }
    __syncthreads();
  }
  const int er = (lane >> 4) * 4, ec = lane & 15;
  #pragma unroll
  for (int i = 0; i < 4; ++i)
    #pragma unroll
    for (int j = 0; j < 4; ++j) {
      const int gr = m0 + wr + i*16 + er;
      const int gc = n0 + wc + j*16 + ec;
      #pragma unroll
      for (int e = 0; e < 4; ++e)
        P[(size_t)(gr + e) * ldc + gc] = f2bf(acc[i][j][e]);
    }
}

// ---------------------------------------------------------------------------
// GEMM 256x256, read-ahead register pipeline (round-10 proven: 90us gate/up).
//   ph0: rd b1(t)   | stage GB1(t+1) | Q00 | vmcnt(6)
//   ph1: rd a1(t)   | stage GA1(t+1) | Q01 | vmcnt(6)
//   ph2: rd a0(t+1) | stage GA0(t+2) | Q10 | vmcnt(6)
//   ph3: rd b0(t+1) | stage GB0(t+2) | Q11 | vmcnt(6)
// Tail peeled with literals 6/6/4/2 then 0. Rect XCD chunks (CX x CY).
// EPI 0: bf16 store. EPI 2: silu(gate)*up fused store (interleaved weights).
// ---------------------------------------------------------------------------
template<int EPI>
__global__ __launch_bounds__(512) void gemm256(const unsigned short* __restrict__ A, int lda,
                                               const unsigned short* __restrict__ BT, int ldb,
                                               void* __restrict__ Cout, int ldc, int K,
                                               int CX, int CY)
{
  __shared__ __align__(16) unsigned short lA[2][256*64];
  __shared__ __align__(16) unsigned short lB[2][256*64];
  const int nx = gridDim.x, ny = gridDim.y;
  const int flat = blockIdx.x + nx * blockIdx.y;
  const int xcd = flat & 7, kk_ = flat >> 3;
  const int RX = nx / CX, RY = ny / CY;
  const int cx = xcd % CX, cy = xcd / CX;
  const int bx = cx * RX + kk_ % RX;
  const int by = cy * RY + kk_ / RX;
  const int tid = threadIdx.x, lane = tid & 63, wid = tid >> 6;
  const int lrow = lane & 15, g = lane >> 4;
  const int wm = wid >> 2, wn = wid & 3;
  const int m0 = by * 256, n0 = bx * 256;

  const int r0 = tid >> 3;
  const int eB = ((r0 >> 5) << 6) | (r0 & 31);
  const int lc0 = ((tid & 7) * 16) ^ ((r0 & 7) << 4);
  const char* pA = (const char*)A + ((size_t)(m0 + r0) * lda) * 2 + lc0;
  const char* pB = (const char*)BT + ((size_t)(n0 + eB) * ldb) * 2 + lc0;
  char* dA = (char*)&lA[0][0] + tid * 16;
  char* dB = (char*)&lB[0][0] + eB * 128 + (tid & 7) * 16;
  const size_t a64 = (size_t)64 * lda * 2;
  const size_t b32 = (size_t)32 * ldb * 2;

#define STG_GA0(t) do { const char* s_ = pA + (size_t)(t) * 128; \
    char* d_ = dA + (((t) & 1) * 32768); \
    gld16(s_, d_); gld16(s_ + 2*a64, d_ + 16384); } while (0)
#define STG_GA1(t) do { const char* s_ = pA + (size_t)(t) * 128 + a64; \
    char* d_ = dA + (((t) & 1) * 32768) + 8192; \
    gld16(s_, d_); gld16(s_ + 2*a64, d_ + 16384); } while (0)
#define STG_GB0(t) do { const char* s_ = pB + (size_t)(t) * 128; \
    char* d_ = dB + (((t) & 1) * 32768); \
    gld16(s_, d_); gld16(s_ + 4*b32, d_ + 16384); } while (0)
#define STG_GB1(t) do { const char* s_ = pB + (size_t)(t) * 128 + b32; \
    char* d_ = dB + (((t) & 1) * 32768) + 4096; \
    gld16(s_, d_); gld16(s_ + 4*b32, d_ + 16384); } while (0)

  const int swz = (lrow & 7) << 4;
  const int c0 = (g * 16) ^ swz;
  const int c1 = c0 ^ 64;
  const char* rdA = (const char*)&lA[0][0] + (wm * 128 + lrow) * 128;
  const char* rdB = (const char*)&lB[0][0] + (wn * 64 + lrow) * 128;

  f32x4 acc[8][4] = {};
  s16x8 a0[4][2], a1[4][2], b0[2][2], b1[2][2];

#define MFMA_Q(rh, ch, AF, BF) do { \
    _Pragma("unroll") \
    for (int i_ = 0; i_ < 4; ++i_) { \
      _Pragma("unroll") \
      for (int j_ = 0; j_ < 2; ++j_) { \
        acc[(rh)*4+i_][(ch)*2+j_] = __builtin_amdgcn_mfma_f32_16x16x32_bf16(AF[i_][0], BF[j_][0], acc[(rh)*4+i_][(ch)*2+j_], 0,0,0); \
        acc[(rh)*4+i_][(ch)*2+j_] = __builtin_amdgcn_mfma_f32_16x16x32_bf16(AF[i_][1], BF[j_][1], acc[(rh)*4+i_][(ch)*2+j_], 0,0,0); \
      } } } while (0)

#define VMCNT(n) asm volatile("s_waitcnt vmcnt(" #n ")" ::: "memory")
#define LGKM0()  do { asm volatile("s_waitcnt lgkmcnt(0)" ::: "memory"); \
                      __builtin_amdgcn_sched_barrier(0); } while (0)
#define BARRIER() do { __builtin_amdgcn_s_barrier(); \
                       __builtin_amdgcn_sched_barrier(0); } while (0)

#define RD_A0(buf) do { _Pragma("unroll") for (int i_ = 0; i_ < 4; ++i_) { \
    a0[i_][0] = *(const s16x8*)((buf) + i_*2048 + c0); \
    a0[i_][1] = *(const s16x8*)((buf) + i_*2048 + c1); } } while (0)
#define RD_A1(buf) do { _Pragma("unroll") for (int i_ = 0; i_ < 4; ++i_) { \
    a1[i_][0] = *(const s16x8*)((buf) + 8192 + i_*2048 + c0); \
    a1[i_][1] = *(const s16x8*)((buf) + 8192 + i_*2048 + c1); } } while (0)
#define RD_B0(buf) do { _Pragma("unroll") for (int j_ = 0; j_ < 2; ++j_) { \
    b0[j_][0] = *(const s16x8*)((buf) + j_*2048 + c0); \
    b0[j_][1] = *(const s16x8*)((buf) + j_*2048 + c1); } } while (0)
#define RD_B1(buf) do { _Pragma("unroll") for (int j_ = 0; j_ < 2; ++j_) { \
    b1[j_][0] = *(const s16x8*)((buf) + 4096 + j_*2048 + c0); \
    b1[j_][1] = *(const s16x8*)((buf) + 4096 + j_*2048 + c1); } } while (0)

#define PRIO_MFMA(rh, ch, AF, BF) do { \
    __builtin_amdgcn_s_setprio(1); MFMA_Q(rh, ch, AF, BF); \
    __builtin_amdgcn_s_setprio(0); } while (0)

  const int NT = K >> 6;   // even, >= 4

  STG_GA0(0); STG_GB0(0); STG_GB1(0); STG_GA1(0); STG_GA0(1); STG_GB0(1);
  VMCNT(6);
  BARRIER();
  RD_A0(rdA); RD_B0(rdB);

  for (int t = 0; t < NT - 2; ++t) {
    const char* Ac = rdA + (t & 1) * 32768;
    const char* Bc = rdB + (t & 1) * 32768;
    const char* An = rdA + ((t & 1) ^ 1) * 32768;
    const char* Bn = rdB + ((t & 1) ^ 1) * 32768;
    LGKM0();
    RD_B1(Bc); STG_GB1(t + 1);
    PRIO_MFMA(0, 0, a0, b0);
    VMCNT(6); BARRIER();
    LGKM0();
    RD_A1(Ac); STG_GA1(t + 1);
    PRIO_MFMA(0, 1, a0, b1);
    VMCNT(6); BARRIER();
    LGKM0();
    RD_A0(An); STG_GA0(t + 2);
    PRIO_MFMA(1, 0, a1, b0);
    VMCNT(6); BARRIER();
    RD_B0(Bn); STG_GB0(t + 2);
    PRIO_MFMA(1, 1, a1, b1);
    VMCNT(6); BARRIER();
  }
  {
    const char* Ac = rdA;
    const char* Bc = rdB;
    const char* An = rdA + 32768;
    const char* Bn = rdB + 32768;
    LGKM0();
    RD_B1(Bc); STG_GB1(NT - 1);
    PRIO_MFMA(0, 0, a0, b0);
    VMCNT(6); BARRIER();
    LGKM0();
    RD_A1(Ac); STG_GA1(NT - 1);
    PRIO_MFMA(0, 1, a0, b1);
    VMCNT(6); BARRIER();
    LGKM0();
    RD_A0(An);
    PRIO_MFMA(1, 0, a1, b0);
    VMCNT(4); BARRIER();
    RD_B0(Bn);
    PRIO_MFMA(1, 1, a1, b1);
    VMCNT(2); BARRIER();
  }
  {
    const char* Ac = rdA + 32768;
    const char* Bc = rdB + 32768;
    LGKM0();
    RD_B1(Bc);
    PRIO_MFMA(0, 0, a0, b0);
    VMCNT(0); BARRIER();
    LGKM0();
    RD_A1(Ac);
    PRIO_MFMA(0, 1, a0, b1);
    LGKM0();
    PRIO_MFMA(1, 0, a1, b0);
    PRIO_MFMA(1, 1, a1, b1);
  }

  const int er = g * 4, ec = lane & 15;
  if (EPI == 0) {
    unsigned short* C = (unsigned short*)Cout;
    #pragma unroll
    for (int i = 0; i < 8; ++i)
      #pragma unroll
      for (int j = 0; j < 4; ++j) {
        const int gr = m0 + wm*128 + i*16 + er;
        const int gc = n0 + wn*64 + j*16 + ec;
        #pragma unroll
        for (int e = 0; e < 4; ++e)
          C[(size_t)(gr + e) * ldc + gc] = f2bf(acc[i][j][e]);
      }
  } else {
    unsigned short* C = (unsigned short*)Cout;
    #pragma unroll
    for (int i = 0; i < 8; ++i)
      #pragma unroll
      for (int tp = 0; tp < 2; ++tp) {
        const int gr = m0 + wm*128 + i*16 + er;
        const int hc = (n0 >> 1) + wn*32 + tp*16 + ec;
        #pragma unroll
        for (int e = 0; e < 4; ++e) {
          const float gv = acc[i][2*tp][e];
          const float uv = acc[i][2*tp + 1][e];
          const float hv = gv / (1.f + __expf(-gv)) * uv;
          C[(size_t)(gr + e) * ldc + hc] = f2bf(hv);
        }
      }
  }
#undef STG_GA0
#undef STG_GA1
#undef STG_GB0
#undef STG_GB1
#undef MFMA_Q
#undef VMCNT
#undef LGKM0
#undef BARRIER
#undef RD_A0
#undef RD_A1
#undef RD_B0
#undef RD_B1
#undef PRIO_MFMA
}

// ---------------------------------------------------------------------------
// Flash attention (causal), KVBLK=128. grid (T/128, B*H), block 512.
// ---------------------------------------------------------------------------
__global__ __launch_bounds__(512) void attn_fwd(const unsigned short* __restrict__ qkv,
                                                const unsigned short* __restrict__ vt,
                                                unsigned short* __restrict__ outp)
{
  __shared__ __align__(16) unsigned short lK[2][128*64];
  __shared__ __align__(16) unsigned short lV[2][64*128];
  const int nx = gridDim.x;
  const int wsz = xcd_swz_flat();
  const int qblk = wsz % nx;
  const int bh = wsz / nx, b = bh >> 4, h = bh & 15;
  const int tid = threadIdx.x, wid = tid >> 6, lane = tid & 63;
  const int lq = lane & 15, g = lane >> 4;

  const int qrow = qblk*128 + wid*16;
  const int myq = qrow + lq;

  const size_t qbase = ((size_t)(b*TSEQ + myq)) * QKVN + h*HD;
  const s16x8 qf0 = *(const s16x8*)&qkv[qbase + g*8];
  const s16x8 qf1 = *(const s16x8*)&qkv[qbase + 32 + g*8];

  const int pk = tid * 16;
  const int Lk0 = pk ^ (((pk >> 7) & 7) << 4);
  const int Lk1 = (pk + 8192) ^ ((((pk + 8192) >> 7) & 7) << 4);
  const char* ks0 = (const char*)qkv + (((size_t)(b*TSEQ + (Lk0 >> 7))) * QKVN + DIM + h*HD) * 2 + (Lk0 & 127);
  const char* ks1 = (const char*)qkv + (((size_t)(b*TSEQ + (Lk1 >> 7))) * QKVN + DIM + h*HD) * 2 + (Lk1 & 127);
  const int Lv0 = pk ^ (((pk >> 8) & 7) << 4);
  const int Lv1 = (pk + 8192) ^ ((((pk + 8192) >> 8) & 7) << 4);
  const char* vs0 = (const char*)vt + (((size_t)bh*HD + (Lv0 >> 8)) * TSEQ) * 2 + (Lv0 & 255);
  const char* vs1 = (const char*)vt + (((size_t)bh*HD + (Lv1 >> 8)) * TSEQ) * 2 + (Lv1 & 255);

#define STAGE_KV(kt, buf) do { \
    gld16(ks0 + (size_t)(kt)*128*(QKVN*2), (char*)lK[buf] + pk); \
    gld16(ks1 + (size_t)(kt)*128*(QKVN*2), (char*)lK[buf] + pk + 8192); \
    gld16(vs0 + (size_t)(kt)*256,          (char*)lV[buf] + pk); \
    gld16(vs1 + (size_t)(kt)*256,          (char*)lV[buf] + pk + 8192); } while (0)

  float mrun = -INFINITY, lrun = 0.f;
  f32x4 of[4] = {};

  const int nkt = qblk + 1;

  STAGE_KV(0, 0);
  int cur = 0;

  for (int kt = 0; kt < nkt; ++kt) {
    __syncthreads();
    if (kt + 1 < nkt) STAGE_KV(kt + 1, cur ^ 1);
    {
      const char* Kb = (const char*)lK[cur];
      const char* Vb = (const char*)lV[cur];
      f32x4 sacc[8];
      __builtin_amdgcn_s_setprio(1);
      #pragma unroll
      for (int s = 0; s < 8; ++s) {
        const int r = s*16 + lq;
        const int sw = (r & 7) << 4;
        const s16x8 kf0 = *(const s16x8*)(Kb + r*128 + ((g*16) ^ sw));
        const s16x8 kf1 = *(const s16x8*)(Kb + r*128 + ((64 + g*16) ^ sw));
        f32x4 z = {0.f,0.f,0.f,0.f};
        z = __builtin_amdgcn_mfma_f32_16x16x32_bf16(kf0, qf0, z, 0,0,0);
        z = __builtin_amdgcn_mfma_f32_16x16x32_bf16(kf1, qf1, z, 0,0,0);
        sacc[s] = z;
      }
      __builtin_amdgcn_s_setprio(0);
      float p[8][4];
      float mt = -INFINITY;
      #pragma unroll
      for (int s = 0; s < 8; ++s)
        #pragma unroll
        for (int e = 0; e < 4; ++e) {
          const int key = kt*128 + s*16 + 4*g + e;
          const float v = (key <= myq) ? sacc[s][e]*0.125f : -INFINITY;
          p[s][e] = v;
          mt = fmaxf(mt, v);
        }
      mt = fmaxf(mt, __shfl_xor(mt, 16));
      mt = fmaxf(mt, __shfl_xor(mt, 32));
      const float mnew = fmaxf(mrun, mt);
      const float scale = __expf(mrun - mnew);
      float ssum = 0.f;
      #pragma unroll
      for (int s = 0; s < 8; ++s)
        #pragma unroll
        for (int e = 0; e < 4; ++e) {
          p[s][e] = __expf(p[s][e] - mnew);
          ssum += p[s][e];
        }
      ssum += __shfl_xor(ssum, 16);
      ssum += __shfl_xor(ssum, 32);
      lrun = lrun * scale + ssum;
      mrun = mnew;
      #pragma unroll
      for (int d0b = 0; d0b < 4; ++d0b) of[d0b] = of[d0b] * scale;
      #pragma unroll
      for (int hh = 0; hh < 4; ++hh) {
        unsigned w[4];
        #pragma unroll
        for (int j = 0; j < 4; ++j) w[j] = pack_bf2(p[2*hh][j], p[2*hh+1][j]);
        s16x8 bp;
        #pragma unroll
        for (int e = 0; e < 8; ++e) {
          const int srcg = 2*(g & 1) + (e >> 2);
          const unsigned ww = (unsigned)__shfl((int)w[e & 3], lq | (srcg << 4));
          bp[e] = (short)((g >= 2) ? (ww >> 16) : (ww & 0xffffu));
        }
        __builtin_amdgcn_s_setprio(1);
        #pragma unroll
        for (int d0b = 0; d0b < 4; ++d0b) {
          const int r = d0b*16 + lq;
          const int sw = (r & 7) << 4;
          const s16x8 vf = *(const s16x8*)(Vb + r*256 + ((hh*64 + g*16) ^ sw));
          of[d0b] = __builtin_amdgcn_mfma_f32_16x16x32_bf16(vf, bp, of[d0b], 0,0,0);
        }
        __builtin_amdgcn_s_setprio(0);
      }
    }
    cur ^= 1;
  }
  const float inv = 1.f / lrun;
  const size_t obase = ((size_t)(b*TSEQ + myq)) * DIM + h*HD;
  #pragma unroll
  for (int d0b = 0; d0b < 4; ++d0b) {
    ushort4 o;
    o.x = f2bf(of[d0b][0] * inv);
    o.y = f2bf(of[d0b][1] * inv);
    o.z = f2bf(of[d0b][2] * inv);
    o.w = f2bf(of[d0b][3] * inv);
    *(ushort4*)&outp[obase + d0b*16 + 4*g] = o;
  }
#undef STAGE_KV
}

// ---------------------------------------------------------------------------
extern "C" void kernel_launch(void* const* d_in, const int* in_sizes, int n_in,
                              void* d_out, int out_size, void* d_ws, size_t ws_size,
                              hipStream_t stream)
{
  const float* x   = (const float*)d_in[0];
  const float* wq  = (const float*)d_in[1];
  const float* wk  = (const float*)d_in[2];
  const float* wv  = (const float*)d_in[3];
  const float* wo  = (const float*)d_in[4];
  const float* wg  = (const float*)d_in[5];
  const float* wu  = (const float*)d_in[6];
  const float* wd  = (const float*)d_in[7];
  const float* anw = (const float*)d_in[8];
  const float* fnw = (const float*)d_in[9];
  float* outp = (float*)d_out;

  const size_t MB = 1024*1024;
  const size_t RD = (size_t)ROWS * DIM;
  char* ws = (char*)d_ws;
  float*          x1    = (float*)         (ws + 0);
  unsigned short* wdT   = (unsigned short*)(ws + 16*MB);
  unsigned short* wguT  = (unsigned short*)(ws + 24*MB);
  unsigned short* wqkvT = (unsigned short*)(ws + 40*MB);
  unsigned short* woT   = (unsigned short*)(ws + 46*MB);
  unsigned short* xn    = (unsigned short*)(ws + 48*MB);
  unsigned short* qkv   = (unsigned short*)(ws + 56*MB);
  unsigned short* vtb   = (unsigned short*)(ws + 80*MB);
  unsigned short* aout  = (unsigned short*)(ws + 88*MB);
  unsigned short* pwo   = (unsigned short*)(ws + 56*MB);   // 2 x 8MB bf16 WO partials
  unsigned short* hbuf  = (unsigned short*)(ws + 56*MB);   // 32MB
  unsigned short* pdn   = (unsigned short*)(ws + 24*MB);   // 4 x 8MB bf16 down partials

  const dim3 blk(256);

  // all weight transposes in one launch
  wtrans_all_k<<<dim3(4096), blk, 0, stream>>>(wq, wk, wv, wo, wg, wu, wd,
                                               wqkvT, woT, wguT, wdT);

  // attention path
  rmsnorm_k<<<ROWS, blk, 0, stream>>>(x, anw, xn);
  gemm128sp<1><<<dim3(QKVN/128, ROWS/128, 1), blk, 0, stream>>>(xn, DIM, wqkvT, DIM, qkv, QKVN, DIM);
  vtrans_k<<<dim3(TSEQ/64, BATCH*NH), blk, 0, stream>>>(qkv, vtb);
  attn_fwd<<<dim3(TSEQ/128, BATCH*NH), dim3(512), 0, stream>>>(qkv, vtb, aout);
  gemm128sp<2><<<dim3(DIM/128, ROWS/128, 2), blk, 0, stream>>>(aout, DIM, woT, DIM, pwo, DIM, DIM/2);
  rmsnorm3_k<<<ROWS, blk, 0, stream>>>(x, pwo, pwo + RD, fnw, x1, xn);

  // ffn path: gate/up on gemm256 with fused silu epilogue (best measured)
  gemm256<2><<<dim3(2*FFN/256, ROWS/256), dim3(512), 0, stream>>>(xn, DIM, wguT, DIM, hbuf, FFN, DIM, 4, 2);
  gemm128sp<4><<<dim3(DIM/128, ROWS/128, 4), blk, 0, stream>>>(hbuf, FFN, wdT, FFN, pdn, DIM, FFN/4);
  resadd5_k<<<dim3(ROWS*DIM/1024), blk, 0, stream>>>(x1, pdn, pdn + RD, pdn + 2*RD, pdn + 3*RD, outp);
}

// Round 19
// 281.744 us; speedup vs baseline: 1.0496x; 1.0155x over previous
//
#include <hip/hip_runtime.h>
#include <hip/hip_bf16.h>
#include <stdint.h>
#include <math.h>

#define DIM   1024
#define TSEQ  2048
#define BATCH 2
#define NH    16
#define HD    64
#define FFN   4096
#define ROWS  (BATCH*TSEQ)   /* 4096 */
#define QKVN  (3*DIM)        /* 3072 */

typedef __attribute__((ext_vector_type(8))) short s16x8;
typedef __attribute__((ext_vector_type(4))) float f32x4;

__device__ __forceinline__ unsigned short f2bf(float f) {
  union { float f; unsigned u; } v; v.f = f;
  unsigned r = v.u + 0x7fffu + ((v.u >> 16) & 1u);
  return (unsigned short)(r >> 16);
}
__device__ __forceinline__ float bf2f(unsigned short h) {
  union { unsigned u; float f; } v; v.u = ((unsigned)h) << 16; return v.f;
}
__device__ __forceinline__ unsigned pack_bf2(float lo, float hi) {
  union { float f; unsigned u; } a, c; a.f = lo; c.f = hi;
  return (c.u & 0xffff0000u) | (a.u >> 16);
}

__device__ __forceinline__ void gld16(const void* g, void* l) {
  __builtin_amdgcn_global_load_lds((const __attribute__((address_space(1))) void*)g,
                                   (__attribute__((address_space(3))) void*)l, 16, 0, 0);
}

// XCD-aware chunked swizzle (m157, linear): valid when nwg % 8 == 0.
__device__ __forceinline__ int xcd_swz_flat() {
  const int nx = gridDim.x, ny = gridDim.y;
  const int nwg = nx * ny * gridDim.z;
  const int flat = blockIdx.x + nx * (blockIdx.y + ny * blockIdx.z);
  return (flat & 7) * (nwg >> 3) + (flat >> 3);
}

// ---------------------------------------------------------------------------
// Mega weight transpose: ALL 7 weights in one launch. 4096 blocks, 256 thr.
// ---------------------------------------------------------------------------
__global__ void wtrans_all_k(const float* __restrict__ wq, const float* __restrict__ wk,
                             const float* __restrict__ wv, const float* __restrict__ wo,
                             const float* __restrict__ wg, const float* __restrict__ wu,
                             const float* __restrict__ wd,
                             unsigned short* __restrict__ wqkvT, unsigned short* __restrict__ woT,
                             unsigned short* __restrict__ wguT, unsigned short* __restrict__ wdT)
{
  __shared__ unsigned short t[64][65];
  const int id = blockIdx.x;
  const float* w; unsigned short* dst; int K, N, mode, n0, k0;
  if (id < 768) {
    const int z = id >> 8, rem = id & 255;
    w = (z == 0) ? wq : (z == 1) ? wk : wv;
    dst = wqkvT + (size_t)z * 1024 * 1024;
    K = 1024; N = 1024; mode = 0;
    n0 = (rem & 15) * 64; k0 = (rem >> 4) * 64;
  } else if (id < 1024) {
    const int rem = id - 768;
    w = wo; dst = woT; K = 1024; N = 1024; mode = 0;
    n0 = (rem & 15) * 64; k0 = (rem >> 4) * 64;
  } else if (id < 2048) {
    const int rem = id - 1024;
    w = wg; dst = wguT; K = 1024; N = FFN; mode = 1;
    n0 = (rem & 63) * 64; k0 = (rem >> 6) * 64;
  } else if (id < 3072) {
    const int rem = id - 2048;
    w = wu; dst = wguT; K = 1024; N = FFN; mode = 2;
    n0 = (rem & 63) * 64; k0 = (rem >> 6) * 64;
  } else {
    const int rem = id - 3072;
    w = wd; dst = wdT; K = FFN; N = 1024; mode = 0;
    n0 = (rem & 15) * 64; k0 = (rem >> 4) * 64;
  }
  const int tid = threadIdx.x;
  #pragma unroll
  for (int i = 0; i < 16; ++i) {
    const int r = i*4 + (tid >> 6), c = tid & 63;
    t[r][c] = f2bf(w[(size_t)(k0 + r) * N + n0 + c]);
  }
  __syncthreads();
  #pragma unroll
  for (int i = 0; i < 16; ++i) {
    const int r = i*4 + (tid >> 6), c = tid & 63;
    const int n = n0 + r;
    int dr = n;
    if (mode == 1) dr = ((n >> 4) << 5) + (n & 15);
    if (mode == 2) dr = ((n >> 4) << 5) + 16 + (n & 15);
    dst[(size_t)dr * K + k0 + c] = t[c][r];
  }
}

// ---------------------------------------------------------------------------
// RMSNorm: x [ROWS][DIM] fp32 -> out bf16. grid ROWS, block 256.
// ---------------------------------------------------------------------------
__global__ void rmsnorm_k(const float* __restrict__ x, const float* __restrict__ w,
                          unsigned short* __restrict__ o)
{
  const int row = blockIdx.x, tid = threadIdx.x;
  const float4 v = ((const float4*)(x + (size_t)row * DIM))[tid];
  float ss = v.x*v.x + v.y*v.y + v.z*v.z + v.w*v.w;
  #pragma unroll
  for (int off = 32; off >= 1; off >>= 1) ss += __shfl_xor(ss, off);
  __shared__ float sred[4];
  if ((tid & 63) == 0) sred[tid >> 6] = ss;
  __syncthreads();
  const float tot = sred[0] + sred[1] + sred[2] + sred[3];
  const float r = rsqrtf(tot * (1.0f/DIM) + 1e-6f);
  const float4 wv = ((const float4*)w)[tid];
  ushort4 ov;
  ov.x = f2bf(v.x*r*wv.x); ov.y = f2bf(v.y*r*wv.y);
  ov.z = f2bf(v.z*r*wv.z); ov.w = f2bf(v.w*r*wv.w);
  ((ushort4*)(o + (size_t)row * DIM))[tid] = ov;
}

// ---------------------------------------------------------------------------
// RMSNorm3: x1 = x + p0 + p1 (bf16 partials); xn = rmsnorm(x1)*w (bf16).
// ---------------------------------------------------------------------------
__global__ void rmsnorm3_k(const float* __restrict__ x, const unsigned short* __restrict__ p0,
                           const unsigned short* __restrict__ p1, const float* __restrict__ w,
                           float* __restrict__ x1, unsigned short* __restrict__ o)
{
  const int row = blockIdx.x, tid = threadIdx.x;
  const size_t base = (size_t)row * DIM;
  const float4 a = ((const float4*)(x + base))[tid];
  const ushort4 b = ((const ushort4*)(p0 + base))[tid];
  const ushort4 c = ((const ushort4*)(p1 + base))[tid];
  float4 v;
  v.x = a.x + bf2f(b.x) + bf2f(c.x); v.y = a.y + bf2f(b.y) + bf2f(c.y);
  v.z = a.z + bf2f(b.z) + bf2f(c.z); v.w = a.w + bf2f(b.w) + bf2f(c.w);
  ((float4*)(x1 + base))[tid] = v;
  float ss = v.x*v.x + v.y*v.y + v.z*v.z + v.w*v.w;
  #pragma unroll
  for (int off = 32; off >= 1; off >>= 1) ss += __shfl_xor(ss, off);
  __shared__ float sred[4];
  if ((tid & 63) == 0) sred[tid >> 6] = ss;
  __syncthreads();
  const float tot = sred[0] + sred[1] + sred[2] + sred[3];
  const float r = rsqrtf(tot * (1.0f/DIM) + 1e-6f);
  const float4 wv = ((const float4*)w)[tid];
  ushort4 ov;
  ov.x = f2bf(v.x*r*wv.x); ov.y = f2bf(v.y*r*wv.y);
  ov.z = f2bf(v.z*r*wv.z); ov.w = f2bf(v.w*r*wv.w);
  ((ushort4*)(o + base))[tid] = ov;
}

// ---------------------------------------------------------------------------
// Final reduce: out = x1 + q0+q1+q2+q3 (bf16 partials). grid 4096, block 256.
// ---------------------------------------------------------------------------
__global__ void resadd5_k(const float* __restrict__ x1,
                          const unsigned short* __restrict__ q0, const unsigned short* __restrict__ q1,
                          const unsigned short* __restrict__ q2, const unsigned short* __restrict__ q3,
                          float* __restrict__ o)
{
  const size_t i = (size_t)blockIdx.x * 256 + threadIdx.x;
  const float4 a = ((const float4*)x1)[i];
  const ushort4 b = ((const ushort4*)q0)[i];
  const ushort4 c = ((const ushort4*)q1)[i];
  const ushort4 d = ((const ushort4*)q2)[i];
  const ushort4 e = ((const ushort4*)q3)[i];
  float4 v;
  v.x = a.x + bf2f(b.x) + bf2f(c.x) + bf2f(d.x) + bf2f(e.x);
  v.y = a.y + bf2f(b.y) + bf2f(c.y) + bf2f(d.y) + bf2f(e.y);
  v.z = a.z + bf2f(b.z) + bf2f(c.z) + bf2f(d.z) + bf2f(e.z);
  v.w = a.w + bf2f(b.w) + bf2f(c.w) + bf2f(d.w) + bf2f(e.w);
  ((float4*)o)[i] = v;
}

// ---------------------------------------------------------------------------
// GEMM 128x128 split-K (m97 structure + XCD swizzle). grid (N/128, M/128, NS).
// EPI 0: bf16 store (NS=1 direct, NS>1 partials at P + bz*M*ldc).
// EPI 2 (QKV+fused V-transpose): blocks with n0+wc >= 2048 write their frags
//   transposed into VT[bh][d][t] (acc[i][j][e] = V[t+e][h*64+d]; e-contiguous
//   in t -> one ushort4 store per frag). Q/K blocks store normally.
// ---------------------------------------------------------------------------
template<int NS, int EPI>
__global__ void gemm128sp(const unsigned short* __restrict__ A, int lda,
                          const unsigned short* __restrict__ BT, int ldb,
                          unsigned short* __restrict__ P, int ldc, int Ksp,
                          unsigned short* __restrict__ VT)
{
  __shared__ __align__(16) unsigned short lA[128*64];
  __shared__ __align__(16) unsigned short lB[128*64];
  const int nx = gridDim.x, ny = gridDim.y;
  const int w = xcd_swz_flat();
  const int bx = w % nx, by = (w / nx) % ny, bz = w / (nx * ny);
  const int tid = threadIdx.x;
  const int lane = tid & 63;
  const int wid = tid >> 6;
  const int m0 = by * 128, n0 = bx * 128;
  const int Koff = bz * Ksp;
  P += (size_t)bz * ((size_t)ny * 128) * ldc;
  const int wr = (wid >> 1) * 64, wc = (wid & 1) * 64;
  const int lrow = lane & 15, lk8 = (lane >> 4) * 8;

  f32x4 acc[4][4] = {};

  for (int k0 = Koff; k0 < Koff + Ksp; k0 += 64) {
    #pragma unroll
    for (int c = 0; c < 4; ++c) {
      const int boff = c*4096 + tid*16;
      const int row = boff >> 7, colb = boff & 127;
      gld16((const char*)A + ((size_t)(m0+row)*lda + k0)*2 + colb, (char*)lA + boff);
    }
    #pragma unroll
    for (int c = 0; c < 4; ++c) {
      const int boff = c*4096 + tid*16;
      const int row = boff >> 7, colb = boff & 127;
      gld16((const char*)BT + ((size_t)(n0+row)*ldb + k0)*2 + colb, (char*)lB + boff);
    }
    __syncthreads();
    #pragma unroll
    for (int kk = 0; kk < 64; kk += 32) {
      s16x8 af[4], bf[4];
      #pragma unroll
      for (int i = 0; i < 4; ++i) af[i] = *(const s16x8*)&lA[(wr + i*16 + lrow)*64 + kk + lk8];
      #pragma unroll
      for (int j = 0; j < 4; ++j) bf[j] = *(const s16x8*)&lB[(wc + j*16 + lrow)*64 + kk + lk8];
      #pragma unroll
      for (int i = 0; i < 4; ++i)
        #pragma unroll
        for (int j = 0; j < 4; ++j)
          acc[i][j] = __builtin_amdgcn_mfma_f32_16x16x32_bf16(af[i], bf[j], acc[i][j], 0, 0, 0);
    }
    __syncthreads();
  }
  const int er = (lane >> 4) * 4, ec = lane & 15;
  if (EPI == 2 && n0 + wc >= 2*DIM) {
    // V block: transposed store into VT[bh][d][t]
    #pragma unroll
    for (int i = 0; i < 4; ++i)
      #pragma unroll
      for (int j = 0; j < 4; ++j) {
        const int gr = m0 + wr + i*16 + er;
        const int vcol = n0 + wc + j*16 + ec - 2*DIM;
        const int hh = vcol >> 6, dd = vcol & 63;
        const int bb = gr >> 11, tt = gr & 2047;
        ushort4 o;
        o.x = f2bf(acc[i][j][0]); o.y = f2bf(acc[i][j][1]);
        o.z = f2bf(acc[i][j][2]); o.w = f2bf(acc[i][j][3]);
        *(ushort4*)&VT[(((size_t)(bb*16 + hh)) * 64 + dd) * 2048 + tt] = o;
      }
  } else {
    #pragma unroll
    for (int i = 0; i < 4; ++i)
      #pragma unroll
      for (int j = 0; j < 4; ++j) {
        const int gr = m0 + wr + i*16 + er;
        const int gc = n0 + wc + j*16 + ec;
        #pragma unroll
        for (int e = 0; e < 4; ++e)
          P[(size_t)(gr + e) * ldc + gc] = f2bf(acc[i][j][e]);
      }
  }
}

// ---------------------------------------------------------------------------
// GEMM 256x256, read-ahead register pipeline (round-10 proven: 90us gate/up).
// EPI 0: bf16 store. EPI 2: silu(gate)*up fused store (interleaved weights).
// ---------------------------------------------------------------------------
template<int EPI>
__global__ __launch_bounds__(512) void gemm256(const unsigned short* __restrict__ A, int lda,
                                               const unsigned short* __restrict__ BT, int ldb,
                                               void* __restrict__ Cout, int ldc, int K,
                                               int CX, int CY)
{
  __shared__ __align__(16) unsigned short lA[2][256*64];
  __shared__ __align__(16) unsigned short lB[2][256*64];
  const int nx = gridDim.x, ny = gridDim.y;
  const int flat = blockIdx.x + nx * blockIdx.y;
  const int xcd = flat & 7, kk_ = flat >> 3;
  const int RX = nx / CX, RY = ny / CY;
  const int cx = xcd % CX, cy = xcd / CX;
  const int bx = cx * RX + kk_ % RX;
  const int by = cy * RY + kk_ / RX;
  const int tid = threadIdx.x, lane = tid & 63, wid = tid >> 6;
  const int lrow = lane & 15, g = lane >> 4;
  const int wm = wid >> 2, wn = wid & 3;
  const int m0 = by * 256, n0 = bx * 256;

  const int r0 = tid >> 3;
  const int eB = ((r0 >> 5) << 6) | (r0 & 31);
  const int lc0 = ((tid & 7) * 16) ^ ((r0 & 7) << 4);
  const char* pA = (const char*)A + ((size_t)(m0 + r0) * lda) * 2 + lc0;
  const char* pB = (const char*)BT + ((size_t)(n0 + eB) * ldb) * 2 + lc0;
  char* dA = (char*)&lA[0][0] + tid * 16;
  char* dB = (char*)&lB[0][0] + eB * 128 + (tid & 7) * 16;
  const size_t a64 = (size_t)64 * lda * 2;
  const size_t b32 = (size_t)32 * ldb * 2;

#define STG_GA0(t) do { const char* s_ = pA + (size_t)(t) * 128; \
    char* d_ = dA + (((t) & 1) * 32768); \
    gld16(s_, d_); gld16(s_ + 2*a64, d_ + 16384); } while (0)
#define STG_GA1(t) do { const char* s_ = pA + (size_t)(t) * 128 + a64; \
    char* d_ = dA + (((t) & 1) * 32768) + 8192; \
    gld16(s_, d_); gld16(s_ + 2*a64, d_ + 16384); } while (0)
#define STG_GB0(t) do { const char* s_ = pB + (size_t)(t) * 128; \
    char* d_ = dB + (((t) & 1) * 32768); \
    gld16(s_, d_); gld16(s_ + 4*b32, d_ + 16384); } while (0)
#define STG_GB1(t) do { const char* s_ = pB + (size_t)(t) * 128 + b32; \
    char* d_ = dB + (((t) & 1) * 32768) + 4096; \
    gld16(s_, d_); gld16(s_ + 4*b32, d_ + 16384); } while (0)

  const int swz = (lrow & 7) << 4;
  const int c0 = (g * 16) ^ swz;
  const int c1 = c0 ^ 64;
  const char* rdA = (const char*)&lA[0][0] + (wm * 128 + lrow) * 128;
  const char* rdB = (const char*)&lB[0][0] + (wn * 64 + lrow) * 128;

  f32x4 acc[8][4] = {};
  s16x8 a0[4][2], a1[4][2], b0[2][2], b1[2][2];

#define MFMA_Q(rh, ch, AF, BF) do { \
    _Pragma("unroll") \
    for (int i_ = 0; i_ < 4; ++i_) { \
      _Pragma("unroll") \
      for (int j_ = 0; j_ < 2; ++j_) { \
        acc[(rh)*4+i_][(ch)*2+j_] = __builtin_amdgcn_mfma_f32_16x16x32_bf16(AF[i_][0], BF[j_][0], acc[(rh)*4+i_][(ch)*2+j_], 0,0,0); \
        acc[(rh)*4+i_][(ch)*2+j_] = __builtin_amdgcn_mfma_f32_16x16x32_bf16(AF[i_][1], BF[j_][1], acc[(rh)*4+i_][(ch)*2+j_], 0,0,0); \
      } } } while (0)

#define VMCNT(n) asm volatile("s_waitcnt vmcnt(" #n ")" ::: "memory")
#define LGKM0()  do { asm volatile("s_waitcnt lgkmcnt(0)" ::: "memory"); \
                      __builtin_amdgcn_sched_barrier(0); } while (0)
#define BARRIER() do { __builtin_amdgcn_s_barrier(); \
                       __builtin_amdgcn_sched_barrier(0); } while (0)

#define RD_A0(buf) do { _Pragma("unroll") for (int i_ = 0; i_ < 4; ++i_) { \
    a0[i_][0] = *(const s16x8*)((buf) + i_*2048 + c0); \
    a0[i_][1] = *(const s16x8*)((buf) + i_*2048 + c1); } } while (0)
#define RD_A1(buf) do { _Pragma("unroll") for (int i_ = 0; i_ < 4; ++i_) { \
    a1[i_][0] = *(const s16x8*)((buf) + 8192 + i_*2048 + c0); \
    a1[i_][1] = *(const s16x8*)((buf) + 8192 + i_*2048 + c1); } } while (0)
#define RD_B0(buf) do { _Pragma("unroll") for (int j_ = 0; j_ < 2; ++j_) { \
    b0[j_][0] = *(const s16x8*)((buf) + j_*2048 + c0); \
    b0[j_][1] = *(const s16x8*)((buf) + j_*2048 + c1); } } while (0)
#define RD_B1(buf) do { _Pragma("unroll") for (int j_ = 0; j_ < 2; ++j_) { \
    b1[j_][0] = *(const s16x8*)((buf) + 4096 + j_*2048 + c0); \
    b1[j_][1] = *(const s16x8*)((buf) + 4096 + j_*2048 + c1); } } while (0)

#define PRIO_MFMA(rh, ch, AF, BF) do { \
    __builtin_amdgcn_s_setprio(1); MFMA_Q(rh, ch, AF, BF); \
    __builtin_amdgcn_s_setprio(0); } while (0)

  const int NT = K >> 6;   // even, >= 4

  STG_GA0(0); STG_GB0(0); STG_GB1(0); STG_GA1(0); STG_GA0(1); STG_GB0(1);
  VMCNT(6);
  BARRIER();
  RD_A0(rdA); RD_B0(rdB);

  for (int t = 0; t < NT - 2; ++t) {
    const char* Ac = rdA + (t & 1) * 32768;
    const char* Bc = rdB + (t & 1) * 32768;
    const char* An = rdA + ((t & 1) ^ 1) * 32768;
    const char* Bn = rdB + ((t & 1) ^ 1) * 32768;
    LGKM0();
    RD_B1(Bc); STG_GB1(t + 1);
    PRIO_MFMA(0, 0, a0, b0);
    VMCNT(6); BARRIER();
    LGKM0();
    RD_A1(Ac); STG_GA1(t + 1);
    PRIO_MFMA(0, 1, a0, b1);
    VMCNT(6); BARRIER();
    LGKM0();
    RD_A0(An); STG_GA0(t + 2);
    PRIO_MFMA(1, 0, a1, b0);
    VMCNT(6); BARRIER();
    RD_B0(Bn); STG_GB0(t + 2);
    PRIO_MFMA(1, 1, a1, b1);
    VMCNT(6); BARRIER();
  }
  {
    const char* Ac = rdA;
    const char* Bc = rdB;
    const char* An = rdA + 32768;
    const char* Bn = rdB + 32768;
    LGKM0();
    RD_B1(Bc); STG_GB1(NT - 1);
    PRIO_MFMA(0, 0, a0, b0);
    VMCNT(6); BARRIER();
    LGKM0();
    RD_A1(Ac); STG_GA1(NT - 1);
    PRIO_MFMA(0, 1, a0, b1);
    VMCNT(6); BARRIER();
    LGKM0();
    RD_A0(An);
    PRIO_MFMA(1, 0, a1, b0);
    VMCNT(4); BARRIER();
    RD_B0(Bn);
    PRIO_MFMA(1, 1, a1, b1);
    VMCNT(2); BARRIER();
  }
  {
    const char* Ac = rdA + 32768;
    const char* Bc = rdB + 32768;
    LGKM0();
    RD_B1(Bc);
    PRIO_MFMA(0, 0, a0, b0);
    VMCNT(0); BARRIER();
    LGKM0();
    RD_A1(Ac);
    PRIO_MFMA(0, 1, a0, b1);
    LGKM0();
    PRIO_MFMA(1, 0, a1, b0);
    PRIO_MFMA(1, 1, a1, b1);
  }

  const int er = g * 4, ec = lane & 15;
  if (EPI == 0) {
    unsigned short* C = (unsigned short*)Cout;
    #pragma unroll
    for (int i = 0; i < 8; ++i)
      #pragma unroll
      for (int j = 0; j < 4; ++j) {
        const int gr = m0 + wm*128 + i*16 + er;
        const int gc = n0 + wn*64 + j*16 + ec;
        #pragma unroll
        for (int e = 0; e < 4; ++e)
          C[(size_t)(gr + e) * ldc + gc] = f2bf(acc[i][j][e]);
      }
  } else {
    unsigned short* C = (unsigned short*)Cout;
    #pragma unroll
    for (int i = 0; i < 8; ++i)
      #pragma unroll
      for (int tp = 0; tp < 2; ++tp) {
        const int gr = m0 + wm*128 + i*16 + er;
        const int hc = (n0 >> 1) + wn*32 + tp*16 + ec;
        #pragma unroll
        for (int e = 0; e < 4; ++e) {
          const float gv = acc[i][2*tp][e];
          const float uv = acc[i][2*tp + 1][e];
          const float hv = gv / (1.f + __expf(-gv)) * uv;
          C[(size_t)(gr + e) * ldc + hc] = f2bf(hv);
        }
      }
  }
#undef STG_GA0
#undef STG_GA1
#undef STG_GB0
#undef STG_GB1
#undef MFMA_Q
#undef VMCNT
#undef LGKM0
#undef BARRIER
#undef RD_A0
#undef RD_A1
#undef RD_B0
#undef RD_B1
#undef PRIO_MFMA
}

// ---------------------------------------------------------------------------
// Flash attention (causal), KVBLK=128. grid (T/128, B*H), block 512.
// ---------------------------------------------------------------------------
__global__ __launch_bounds__(512) void attn_fwd(const unsigned short* __restrict__ qkv,
                                                const unsigned short* __restrict__ vt,
                                                unsigned short* __restrict__ outp)
{
  __shared__ __align__(16) unsigned short lK[2][128*64];
  __shared__ __align__(16) unsigned short lV[2][64*128];
  const int nx = gridDim.x;
  const int wsz = xcd_swz_flat();
  const int qblk = wsz % nx;
  const int bh = wsz / nx, b = bh >> 4, h = bh & 15;
  const int tid = threadIdx.x, wid = tid >> 6, lane = tid & 63;
  const int lq = lane & 15, g = lane >> 4;

  const int qrow = qblk*128 + wid*16;
  const int myq = qrow + lq;

  const size_t qbase = ((size_t)(b*TSEQ + myq)) * QKVN + h*HD;
  const s16x8 qf0 = *(const s16x8*)&qkv[qbase + g*8];
  const s16x8 qf1 = *(const s16x8*)&qkv[qbase + 32 + g*8];

  const int pk = tid * 16;
  const int Lk0 = pk ^ (((pk >> 7) & 7) << 4);
  const int Lk1 = (pk + 8192) ^ ((((pk + 8192) >> 7) & 7) << 4);
  const char* ks0 = (const char*)qkv + (((size_t)(b*TSEQ + (Lk0 >> 7))) * QKVN + DIM + h*HD) * 2 + (Lk0 & 127);
  const char* ks1 = (const char*)qkv + (((size_t)(b*TSEQ + (Lk1 >> 7))) * QKVN + DIM + h*HD) * 2 + (Lk1 & 127);
  const int Lv0 = pk ^ (((pk >> 8) & 7) << 4);
  const int Lv1 = (pk + 8192) ^ ((((pk + 8192) >> 8) & 7) << 4);
  const char* vs0 = (const char*)vt + (((size_t)bh*HD + (Lv0 >> 8)) * TSEQ) * 2 + (Lv0 & 255);
  const char* vs1 = (const char*)vt + (((size_t)bh*HD + (Lv1 >> 8)) * TSEQ) * 2 + (Lv1 & 255);

#define STAGE_KV(kt, buf) do { \
    gld16(ks0 + (size_t)(kt)*128*(QKVN*2), (char*)lK[buf] + pk); \
    gld16(ks1 + (size_t)(kt)*128*(QKVN*2), (char*)lK[buf] + pk + 8192); \
    gld16(vs0 + (size_t)(kt)*256,          (char*)lV[buf] + pk); \
    gld16(vs1 + (size_t)(kt)*256,          (char*)lV[buf] + pk + 8192); } while (0)

  float mrun = -INFINITY, lrun = 0.f;
  f32x4 of[4] = {};

  const int nkt = qblk + 1;

  STAGE_KV(0, 0);
  int cur = 0;

  for (int kt = 0; kt < nkt; ++kt) {
    __syncthreads();
    if (kt + 1 < nkt) STAGE_KV(kt + 1, cur ^ 1);
    {
      const char* Kb = (const char*)lK[cur];
      const char* Vb = (const char*)lV[cur];
      f32x4 sacc[8];
      __builtin_amdgcn_s_setprio(1);
      #pragma unroll
      for (int s = 0; s < 8; ++s) {
        const int r = s*16 + lq;
        const int sw = (r & 7) << 4;
        const s16x8 kf0 = *(const s16x8*)(Kb + r*128 + ((g*16) ^ sw));
        const s16x8 kf1 = *(const s16x8*)(Kb + r*128 + ((64 + g*16) ^ sw));
        f32x4 z = {0.f,0.f,0.f,0.f};
        z = __builtin_amdgcn_mfma_f32_16x16x32_bf16(kf0, qf0, z, 0,0,0);
        z = __builtin_amdgcn_mfma_f32_16x16x32_bf16(kf1, qf1, z, 0,0,0);
        sacc[s] = z;
      }
      __builtin_amdgcn_s_setprio(0);
      float p[8][4];
      float mt = -INFINITY;
      #pragma unroll
      for (int s = 0; s < 8; ++s)
        #pragma unroll
        for (int e = 0; e < 4; ++e) {
          const int key = kt*128 + s*16 + 4*g + e;
          const float v = (key <= myq) ? sacc[s][e]*0.125f : -INFINITY;
          p[s][e] = v;
          mt = fmaxf(mt, v);
        }
      mt = fmaxf(mt, __shfl_xor(mt, 16));
      mt = fmaxf(mt, __shfl_xor(mt, 32));
      const float mnew = fmaxf(mrun, mt);
      const float scale = __expf(mrun - mnew);
      float ssum = 0.f;
      #pragma unroll
      for (int s = 0; s < 8; ++s)
        #pragma unroll
        for (int e = 0; e < 4; ++e) {
          p[s][e] = __expf(p[s][e] - mnew);
          ssum += p[s][e];
        }
      ssum += __shfl_xor(ssum, 16);
      ssum += __shfl_xor(ssum, 32);
      lrun = lrun * scale + ssum;
      mrun = mnew;
      #pragma unroll
      for (int d0b = 0; d0b < 4; ++d0b) of[d0b] = of[d0b] * scale;
      #pragma unroll
      for (int hh = 0; hh < 4; ++hh) {
        unsigned w[4];
        #pragma unroll
        for (int j = 0; j < 4; ++j) w[j] = pack_bf2(p[2*hh][j], p[2*hh+1][j]);
        s16x8 bp;
        #pragma unroll
        for (int e = 0; e < 8; ++e) {
          const int srcg = 2*(g & 1) + (e >> 2);
          const unsigned ww = (unsigned)__shfl((int)w[e & 3], lq | (srcg << 4));
          bp[e] = (short)((g >= 2) ? (ww >> 16) : (ww & 0xffffu));
        }
        __builtin_amdgcn_s_setprio(1);
        #pragma unroll
        for (int d0b = 0; d0b < 4; ++d0b) {
          const int r = d0b*16 + lq;
          const int sw = (r & 7) << 4;
          const s16x8 vf = *(const s16x8*)(Vb + r*256 + ((hh*64 + g*16) ^ sw));
          of[d0b] = __builtin_amdgcn_mfma_f32_16x16x32_bf16(vf, bp, of[d0b], 0,0,0);
        }
        __builtin_amdgcn_s_setprio(0);
      }
    }
    cur ^= 1;
  }
  const float inv = 1.f / lrun;
  const size_t obase = ((size_t)(b*TSEQ + myq)) * DIM + h*HD;
  #pragma unroll
  for (int d0b = 0; d0b < 4; ++d0b) {
    ushort4 o;
    o.x = f2bf(of[d0b][0] * inv);
    o.y = f2bf(of[d0b][1] * inv);
    o.z = f2bf(of[d0b][2] * inv);
    o.w = f2bf(of[d0b][3] * inv);
    *(ushort4*)&outp[obase + d0b*16 + 4*g] = o;
  }
#undef STAGE_KV
}

// ---------------------------------------------------------------------------
extern "C" void kernel_launch(void* const* d_in, const int* in_sizes, int n_in,
                              void* d_out, int out_size, void* d_ws, size_t ws_size,
                              hipStream_t stream)
{
  const float* x   = (const float*)d_in[0];
  const float* wq  = (const float*)d_in[1];
  const float* wk  = (const float*)d_in[2];
  const float* wv  = (const float*)d_in[3];
  const float* wo  = (const float*)d_in[4];
  const float* wg  = (const float*)d_in[5];
  const float* wu  = (const float*)d_in[6];
  const float* wd  = (const float*)d_in[7];
  const float* anw = (const float*)d_in[8];
  const float* fnw = (const float*)d_in[9];
  float* outp = (float*)d_out;

  const size_t MB = 1024*1024;
  const size_t RD = (size_t)ROWS * DIM;
  char* ws = (char*)d_ws;
  float*          x1    = (float*)         (ws + 0);
  unsigned short* wdT   = (unsigned short*)(ws + 16*MB);
  unsigned short* wguT  = (unsigned short*)(ws + 24*MB);
  unsigned short* wqkvT = (unsigned short*)(ws + 40*MB);
  unsigned short* woT   = (unsigned short*)(ws + 46*MB);
  unsigned short* xn    = (unsigned short*)(ws + 48*MB);
  unsigned short* qkv   = (unsigned short*)(ws + 56*MB);
  unsigned short* vtb   = (unsigned short*)(ws + 80*MB);
  unsigned short* aout  = (unsigned short*)(ws + 88*MB);
  unsigned short* pwo   = (unsigned short*)(ws + 56*MB);   // 2 x 8MB bf16 WO partials
  unsigned short* hbuf  = (unsigned short*)(ws + 56*MB);   // 32MB
  unsigned short* pdn   = (unsigned short*)(ws + 24*MB);   // 4 x 8MB bf16 down partials

  const dim3 blk(256);

  // all weight transposes in one launch
  wtrans_all_k<<<dim3(4096), blk, 0, stream>>>(wq, wk, wv, wo, wg, wu, wd,
                                               wqkvT, woT, wguT, wdT);

  // attention path (V-transpose fused into QKV epilogue; vtrans kernel gone)
  rmsnorm_k<<<ROWS, blk, 0, stream>>>(x, anw, xn);
  gemm128sp<1,2><<<dim3(QKVN/128, ROWS/128, 1), blk, 0, stream>>>(xn, DIM, wqkvT, DIM, qkv, QKVN, DIM, vtb);
  attn_fwd<<<dim3(TSEQ/128, BATCH*NH), dim3(512), 0, stream>>>(qkv, vtb, aout);
  gemm128sp<2,0><<<dim3(DIM/128, ROWS/128, 2), blk, 0, stream>>>(aout, DIM, woT, DIM, pwo, DIM, DIM/2, nullptr);
  rmsnorm3_k<<<ROWS, blk, 0, stream>>>(x, pwo, pwo + RD, fnw, x1, xn);

  // ffn path: gate/up on gemm256 with fused silu epilogue (best measured)
  gemm256<2><<<dim3(2*FFN/256, ROWS/256), dim3(512), 0, stream>>>(xn, DIM, wguT, DIM, hbuf, FFN, DIM, 4, 2);
  gemm128sp<4,0><<<dim3(DIM/128, ROWS/128, 4), blk, 0, stream>>>(hbuf, FFN, wdT, FFN, pdn, DIM, FFN/4, nullptr);
  resadd5_k<<<dim3(ROWS*DIM/1024), blk, 0, stream>>>(x1, pdn, pdn + RD, pdn + 2*RD, pdn + 3*RD, outp);
}

// Round 20
// 278.368 us; speedup vs baseline: 1.0624x; 1.0121x over previous
//
#include <hip/hip_runtime.h>
#include <hip/hip_bf16.h>
#include <stdint.h>
#include <math.h>

#define DIM   1024
#define TSEQ  2048
#define BATCH 2
#define NH    16
#define HD    64
#define FFN   4096
#define ROWS  (BATCH*TSEQ)   /* 4096 */
#define QKVN  (3*DIM)        /* 3072 */

typedef __attribute__((ext_vector_type(8))) short s16x8;
typedef __attribute__((ext_vector_type(4))) float f32x4;

__device__ __forceinline__ unsigned short f2bf(float f) {
  union { float f; unsigned u; } v; v.f = f;
  unsigned r = v.u + 0x7fffu + ((v.u >> 16) & 1u);
  return (unsigned short)(r >> 16);
}
__device__ __forceinline__ float bf2f(unsigned short h) {
  union { unsigned u; float f; } v; v.u = ((unsigned)h) << 16; return v.f;
}
__device__ __forceinline__ unsigned pack_bf2(float lo, float hi) {
  union { float f; unsigned u; } a, c; a.f = lo; c.f = hi;
  return (c.u & 0xffff0000u) | (a.u >> 16);
}

__device__ __forceinline__ void gld16(const void* g, void* l) {
  __builtin_amdgcn_global_load_lds((const __attribute__((address_space(1))) void*)g,
                                   (__attribute__((address_space(3))) void*)l, 16, 0, 0);
}

// XCD-aware chunked swizzle (m157, linear): valid when nwg % 8 == 0.
__device__ __forceinline__ int xcd_swz_flat() {
  const int nx = gridDim.x, ny = gridDim.y;
  const int nwg = nx * ny * gridDim.z;
  const int flat = blockIdx.x + nx * (blockIdx.y + ny * blockIdx.z);
  return (flat & 7) * (nwg >> 3) + (flat >> 3);
}

// ---------------------------------------------------------------------------
// Mega prologue kernel: ALL 7 weight transposes + attn RMSNorm in one launch.
// 8192 blocks, 256 thr. id<4096: 64x64 weight transpose tile; id>=4096:
// rmsnorm row (id-4096). Branch is block-uniform; inputs independent.
// ---------------------------------------------------------------------------
__global__ void prologue_k(const float* __restrict__ wq, const float* __restrict__ wk,
                           const float* __restrict__ wv, const float* __restrict__ wo,
                           const float* __restrict__ wg, const float* __restrict__ wu,
                           const float* __restrict__ wd,
                           unsigned short* __restrict__ wqkvT, unsigned short* __restrict__ woT,
                           unsigned short* __restrict__ wguT, unsigned short* __restrict__ wdT,
                           const float* __restrict__ x, const float* __restrict__ anw,
                           unsigned short* __restrict__ xn)
{
  __shared__ unsigned short t[64][65];
  __shared__ float sred[4];
  const int id = blockIdx.x;
  const int tid = threadIdx.x;
  if (id >= 4096) {
    // ---- RMSNorm row
    const int row = id - 4096;
    const float4 v = ((const float4*)(x + (size_t)row * DIM))[tid];
    float ss = v.x*v.x + v.y*v.y + v.z*v.z + v.w*v.w;
    #pragma unroll
    for (int off = 32; off >= 1; off >>= 1) ss += __shfl_xor(ss, off);
    if ((tid & 63) == 0) sred[tid >> 6] = ss;
    __syncthreads();
    const float tot = sred[0] + sred[1] + sred[2] + sred[3];
    const float r = rsqrtf(tot * (1.0f/DIM) + 1e-6f);
    const float4 wv = ((const float4*)anw)[tid];
    ushort4 ov;
    ov.x = f2bf(v.x*r*wv.x); ov.y = f2bf(v.y*r*wv.y);
    ov.z = f2bf(v.z*r*wv.z); ov.w = f2bf(v.w*r*wv.w);
    ((ushort4*)(xn + (size_t)row * DIM))[tid] = ov;
    return;
  }
  // ---- weight transpose tile
  const float* w; unsigned short* dst; int K, N, mode, n0, k0;
  if (id < 768) {
    const int z = id >> 8, rem = id & 255;
    w = (z == 0) ? wq : (z == 1) ? wk : wv;
    dst = wqkvT + (size_t)z * 1024 * 1024;
    K = 1024; N = 1024; mode = 0;
    n0 = (rem & 15) * 64; k0 = (rem >> 4) * 64;
  } else if (id < 1024) {
    const int rem = id - 768;
    w = wo; dst = woT; K = 1024; N = 1024; mode = 0;
    n0 = (rem & 15) * 64; k0 = (rem >> 4) * 64;
  } else if (id < 2048) {
    const int rem = id - 1024;
    w = wg; dst = wguT; K = 1024; N = FFN; mode = 1;
    n0 = (rem & 63) * 64; k0 = (rem >> 6) * 64;
  } else if (id < 3072) {
    const int rem = id - 2048;
    w = wu; dst = wguT; K = 1024; N = FFN; mode = 2;
    n0 = (rem & 63) * 64; k0 = (rem >> 6) * 64;
  } else {
    const int rem = id - 3072;
    w = wd; dst = wdT; K = FFN; N = 1024; mode = 0;
    n0 = (rem & 15) * 64; k0 = (rem >> 4) * 64;
  }
  #pragma unroll
  for (int i = 0; i < 16; ++i) {
    const int r = i*4 + (tid >> 6), c = tid & 63;
    t[r][c] = f2bf(w[(size_t)(k0 + r) * N + n0 + c]);
  }
  __syncthreads();
  #pragma unroll
  for (int i = 0; i < 16; ++i) {
    const int r = i*4 + (tid >> 6), c = tid & 63;
    const int n = n0 + r;
    int dr = n;
    if (mode == 1) dr = ((n >> 4) << 5) + (n & 15);
    if (mode == 2) dr = ((n >> 4) << 5) + 16 + (n & 15);
    dst[(size_t)dr * K + k0 + c] = t[c][r];
  }
}

// ---------------------------------------------------------------------------
// RMSNorm3: x1 = x + p0 + p1 (bf16 partials); xn = rmsnorm(x1)*w (bf16).
// ---------------------------------------------------------------------------
__global__ void rmsnorm3_k(const float* __restrict__ x, const unsigned short* __restrict__ p0,
                           const unsigned short* __restrict__ p1, const float* __restrict__ w,
                           float* __restrict__ x1, unsigned short* __restrict__ o)
{
  const int row = blockIdx.x, tid = threadIdx.x;
  const size_t base = (size_t)row * DIM;
  const float4 a = ((const float4*)(x + base))[tid];
  const ushort4 b = ((const ushort4*)(p0 + base))[tid];
  const ushort4 c = ((const ushort4*)(p1 + base))[tid];
  float4 v;
  v.x = a.x + bf2f(b.x) + bf2f(c.x); v.y = a.y + bf2f(b.y) + bf2f(c.y);
  v.z = a.z + bf2f(b.z) + bf2f(c.z); v.w = a.w + bf2f(b.w) + bf2f(c.w);
  ((float4*)(x1 + base))[tid] = v;
  float ss = v.x*v.x + v.y*v.y + v.z*v.z + v.w*v.w;
  #pragma unroll
  for (int off = 32; off >= 1; off >>= 1) ss += __shfl_xor(ss, off);
  __shared__ float sred[4];
  if ((tid & 63) == 0) sred[tid >> 6] = ss;
  __syncthreads();
  const float tot = sred[0] + sred[1] + sred[2] + sred[3];
  const float r = rsqrtf(tot * (1.0f/DIM) + 1e-6f);
  const float4 wv = ((const float4*)w)[tid];
  ushort4 ov;
  ov.x = f2bf(v.x*r*wv.x); ov.y = f2bf(v.y*r*wv.y);
  ov.z = f2bf(v.z*r*wv.z); ov.w = f2bf(v.w*r*wv.w);
  ((ushort4*)(o + base))[tid] = ov;
}

// ---------------------------------------------------------------------------
// Final reduce: out = x1 + q0+q1+q2+q3 (bf16 partials). grid 4096, block 256.
// ---------------------------------------------------------------------------
__global__ void resadd5_k(const float* __restrict__ x1,
                          const unsigned short* __restrict__ q0, const unsigned short* __restrict__ q1,
                          const unsigned short* __restrict__ q2, const unsigned short* __restrict__ q3,
                          float* __restrict__ o)
{
  const size_t i = (size_t)blockIdx.x * 256 + threadIdx.x;
  const float4 a = ((const float4*)x1)[i];
  const ushort4 b = ((const ushort4*)q0)[i];
  const ushort4 c = ((const ushort4*)q1)[i];
  const ushort4 d = ((const ushort4*)q2)[i];
  const ushort4 e = ((const ushort4*)q3)[i];
  float4 v;
  v.x = a.x + bf2f(b.x) + bf2f(c.x) + bf2f(d.x) + bf2f(e.x);
  v.y = a.y + bf2f(b.y) + bf2f(c.y) + bf2f(d.y) + bf2f(e.y);
  v.z = a.z + bf2f(b.z) + bf2f(c.z) + bf2f(d.z) + bf2f(e.z);
  v.w = a.w + bf2f(b.w) + bf2f(c.w) + bf2f(d.w) + bf2f(e.w);
  ((float4*)o)[i] = v;
}

// ---------------------------------------------------------------------------
// GEMM 128x128 split-K (m97 structure + XCD swizzle). grid (N/128, M/128, NS).
// EPI 0: bf16 store (NS=1 direct, NS>1 partials at P + bz*M*ldc).
// EPI 2 (QKV+fused V-transpose): blocks with n0+wc >= 2048 write their frags
//   transposed into VT[bh][d][t].
// ---------------------------------------------------------------------------
template<int NS, int EPI>
__global__ void gemm128sp(const unsigned short* __restrict__ A, int lda,
                          const unsigned short* __restrict__ BT, int ldb,
                          unsigned short* __restrict__ P, int ldc, int Ksp,
                          unsigned short* __restrict__ VT)
{
  __shared__ __align__(16) unsigned short lA[128*64];
  __shared__ __align__(16) unsigned short lB[128*64];
  const int nx = gridDim.x, ny = gridDim.y;
  const int w = xcd_swz_flat();
  const int bx = w % nx, by = (w / nx) % ny, bz = w / (nx * ny);
  const int tid = threadIdx.x;
  const int lane = tid & 63;
  const int wid = tid >> 6;
  const int m0 = by * 128, n0 = bx * 128;
  const int Koff = bz * Ksp;
  P += (size_t)bz * ((size_t)ny * 128) * ldc;
  const int wr = (wid >> 1) * 64, wc = (wid & 1) * 64;
  const int lrow = lane & 15, lk8 = (lane >> 4) * 8;

  f32x4 acc[4][4] = {};

  for (int k0 = Koff; k0 < Koff + Ksp; k0 += 64) {
    #pragma unroll
    for (int c = 0; c < 4; ++c) {
      const int boff = c*4096 + tid*16;
      const int row = boff >> 7, colb = boff & 127;
      gld16((const char*)A + ((size_t)(m0+row)*lda + k0)*2 + colb, (char*)lA + boff);
    }
    #pragma unroll
    for (int c = 0; c < 4; ++c) {
      const int boff = c*4096 + tid*16;
      const int row = boff >> 7, colb = boff & 127;
      gld16((const char*)BT + ((size_t)(n0+row)*ldb + k0)*2 + colb, (char*)lB + boff);
    }
    __syncthreads();
    #pragma unroll
    for (int kk = 0; kk < 64; kk += 32) {
      s16x8 af[4], bf[4];
      #pragma unroll
      for (int i = 0; i < 4; ++i) af[i] = *(const s16x8*)&lA[(wr + i*16 + lrow)*64 + kk + lk8];
      #pragma unroll
      for (int j = 0; j < 4; ++j) bf[j] = *(const s16x8*)&lB[(wc + j*16 + lrow)*64 + kk + lk8];
      #pragma unroll
      for (int i = 0; i < 4; ++i)
        #pragma unroll
        for (int j = 0; j < 4; ++j)
          acc[i][j] = __builtin_amdgcn_mfma_f32_16x16x32_bf16(af[i], bf[j], acc[i][j], 0, 0, 0);
    }
    __syncthreads();
  }
  const int er = (lane >> 4) * 4, ec = lane & 15;
  if (EPI == 2 && n0 + wc >= 2*DIM) {
    #pragma unroll
    for (int i = 0; i < 4; ++i)
      #pragma unroll
      for (int j = 0; j < 4; ++j) {
        const int gr = m0 + wr + i*16 + er;
        const int vcol = n0 + wc + j*16 + ec - 2*DIM;
        const int hh = vcol >> 6, dd = vcol & 63;
        const int bb = gr >> 11, tt = gr & 2047;
        ushort4 o;
        o.x = f2bf(acc[i][j][0]); o.y = f2bf(acc[i][j][1]);
        o.z = f2bf(acc[i][j][2]); o.w = f2bf(acc[i][j][3]);
        *(ushort4*)&VT[(((size_t)(bb*16 + hh)) * 64 + dd) * 2048 + tt] = o;
      }
  } else {
    #pragma unroll
    for (int i = 0; i < 4; ++i)
      #pragma unroll
      for (int j = 0; j < 4; ++j) {
        const int gr = m0 + wr + i*16 + er;
        const int gc = n0 + wc + j*16 + ec;
        #pragma unroll
        for (int e = 0; e < 4; ++e)
          P[(size_t)(gr + e) * ldc + gc] = f2bf(acc[i][j][e]);
      }
  }
}

// ---------------------------------------------------------------------------
// GEMM 256x256, read-ahead register pipeline (round-10 proven: 90us gate/up).
// EPI 0: bf16 store. EPI 2: silu(gate)*up fused store (interleaved weights).
// ---------------------------------------------------------------------------
template<int EPI>
__global__ __launch_bounds__(512) void gemm256(const unsigned short* __restrict__ A, int lda,
                                               const unsigned short* __restrict__ BT, int ldb,
                                               void* __restrict__ Cout, int ldc, int K,
                                               int CX, int CY)
{
  __shared__ __align__(16) unsigned short lA[2][256*64];
  __shared__ __align__(16) unsigned short lB[2][256*64];
  const int nx = gridDim.x, ny = gridDim.y;
  const int flat = blockIdx.x + nx * blockIdx.y;
  const int xcd = flat & 7, kk_ = flat >> 3;
  const int RX = nx / CX, RY = ny / CY;
  const int cx = xcd % CX, cy = xcd / CX;
  const int bx = cx * RX + kk_ % RX;
  const int by = cy * RY + kk_ / RX;
  const int tid = threadIdx.x, lane = tid & 63, wid = tid >> 6;
  const int lrow = lane & 15, g = lane >> 4;
  const int wm = wid >> 2, wn = wid & 3;
  const int m0 = by * 256, n0 = bx * 256;

  const int r0 = tid >> 3;
  const int eB = ((r0 >> 5) << 6) | (r0 & 31);
  const int lc0 = ((tid & 7) * 16) ^ ((r0 & 7) << 4);
  const char* pA = (const char*)A + ((size_t)(m0 + r0) * lda) * 2 + lc0;
  const char* pB = (const char*)BT + ((size_t)(n0 + eB) * ldb) * 2 + lc0;
  char* dA = (char*)&lA[0][0] + tid * 16;
  char* dB = (char*)&lB[0][0] + eB * 128 + (tid & 7) * 16;
  const size_t a64 = (size_t)64 * lda * 2;
  const size_t b32 = (size_t)32 * ldb * 2;

#define STG_GA0(t) do { const char* s_ = pA + (size_t)(t) * 128; \
    char* d_ = dA + (((t) & 1) * 32768); \
    gld16(s_, d_); gld16(s_ + 2*a64, d_ + 16384); } while (0)
#define STG_GA1(t) do { const char* s_ = pA + (size_t)(t) * 128 + a64; \
    char* d_ = dA + (((t) & 1) * 32768) + 8192; \
    gld16(s_, d_); gld16(s_ + 2*a64, d_ + 16384); } while (0)
#define STG_GB0(t) do { const char* s_ = pB + (size_t)(t) * 128; \
    char* d_ = dB + (((t) & 1) * 32768); \
    gld16(s_, d_); gld16(s_ + 4*b32, d_ + 16384); } while (0)
#define STG_GB1(t) do { const char* s_ = pB + (size_t)(t) * 128 + b32; \
    char* d_ = dB + (((t) & 1) * 32768) + 4096; \
    gld16(s_, d_); gld16(s_ + 4*b32, d_ + 16384); } while (0)

  const int swz = (lrow & 7) << 4;
  const int c0 = (g * 16) ^ swz;
  const int c1 = c0 ^ 64;
  const char* rdA = (const char*)&lA[0][0] + (wm * 128 + lrow) * 128;
  const char* rdB = (const char*)&lB[0][0] + (wn * 64 + lrow) * 128;

  f32x4 acc[8][4] = {};
  s16x8 a0[4][2], a1[4][2], b0[2][2], b1[2][2];

#define MFMA_Q(rh, ch, AF, BF) do { \
    _Pragma("unroll") \
    for (int i_ = 0; i_ < 4; ++i_) { \
      _Pragma("unroll") \
      for (int j_ = 0; j_ < 2; ++j_) { \
        acc[(rh)*4+i_][(ch)*2+j_] = __builtin_amdgcn_mfma_f32_16x16x32_bf16(AF[i_][0], BF[j_][0], acc[(rh)*4+i_][(ch)*2+j_], 0,0,0); \
        acc[(rh)*4+i_][(ch)*2+j_] = __builtin_amdgcn_mfma_f32_16x16x32_bf16(AF[i_][1], BF[j_][1], acc[(rh)*4+i_][(ch)*2+j_], 0,0,0); \
      } } } while (0)

#define VMCNT(n) asm volatile("s_waitcnt vmcnt(" #n ")" ::: "memory")
#define LGKM0()  do { asm volatile("s_waitcnt lgkmcnt(0)" ::: "memory"); \
                      __builtin_amdgcn_sched_barrier(0); } while (0)
#define BARRIER() do { __builtin_amdgcn_s_barrier(); \
                       __builtin_amdgcn_sched_barrier(0); } while (0)

#define RD_A0(buf) do { _Pragma("unroll") for (int i_ = 0; i_ < 4; ++i_) { \
    a0[i_][0] = *(const s16x8*)((buf) + i_*2048 + c0); \
    a0[i_][1] = *(const s16x8*)((buf) + i_*2048 + c1); } } while (0)
#define RD_A1(buf) do { _Pragma("unroll") for (int i_ = 0; i_ < 4; ++i_) { \
    a1[i_][0] = *(const s16x8*)((buf) + 8192 + i_*2048 + c0); \
    a1[i_][1] = *(const s16x8*)((buf) + 8192 + i_*2048 + c1); } } while (0)
#define RD_B0(buf) do { _Pragma("unroll") for (int j_ = 0; j_ < 2; ++j_) { \
    b0[j_][0] = *(const s16x8*)((buf) + j_*2048 + c0); \
    b0[j_][1] = *(const s16x8*)((buf) + j_*2048 + c1); } } while (0)
#define RD_B1(buf) do { _Pragma("unroll") for (int j_ = 0; j_ < 2; ++j_) { \
    b1[j_][0] = *(const s16x8*)((buf) + 4096 + j_*2048 + c0); \
    b1[j_][1] = *(const s16x8*)((buf) + 4096 + j_*2048 + c1); } } while (0)

#define PRIO_MFMA(rh, ch, AF, BF) do { \
    __builtin_amdgcn_s_setprio(1); MFMA_Q(rh, ch, AF, BF); \
    __builtin_amdgcn_s_setprio(0); } while (0)

  const int NT = K >> 6;   // even, >= 4

  STG_GA0(0); STG_GB0(0); STG_GB1(0); STG_GA1(0); STG_GA0(1); STG_GB0(1);
  VMCNT(6);
  BARRIER();
  RD_A0(rdA); RD_B0(rdB);

  for (int t = 0; t < NT - 2; ++t) {
    const char* Ac = rdA + (t & 1) * 32768;
    const char* Bc = rdB + (t & 1) * 32768;
    const char* An = rdA + ((t & 1) ^ 1) * 32768;
    const char* Bn = rdB + ((t & 1) ^ 1) * 32768;
    LGKM0();
    RD_B1(Bc); STG_GB1(t + 1);
    PRIO_MFMA(0, 0, a0, b0);
    VMCNT(6); BARRIER();
    LGKM0();
    RD_A1(Ac); STG_GA1(t + 1);
    PRIO_MFMA(0, 1, a0, b1);
    VMCNT(6); BARRIER();
    LGKM0();
    RD_A0(An); STG_GA0(t + 2);
    PRIO_MFMA(1, 0, a1, b0);
    VMCNT(6); BARRIER();
    RD_B0(Bn); STG_GB0(t + 2);
    PRIO_MFMA(1, 1, a1, b1);
    VMCNT(6); BARRIER();
  }
  {
    const char* Ac = rdA;
    const char* Bc = rdB;
    const char* An = rdA + 32768;
    const char* Bn = rdB + 32768;
    LGKM0();
    RD_B1(Bc); STG_GB1(NT - 1);
    PRIO_MFMA(0, 0, a0, b0);
    VMCNT(6); BARRIER();
    LGKM0();
    RD_A1(Ac); STG_GA1(NT - 1);
    PRIO_MFMA(0, 1, a0, b1);
    VMCNT(6); BARRIER();
    LGKM0();
    RD_A0(An);
    PRIO_MFMA(1, 0, a1, b0);
    VMCNT(4); BARRIER();
    RD_B0(Bn);
    PRIO_MFMA(1, 1, a1, b1);
    VMCNT(2); BARRIER();
  }
  {
    const char* Ac = rdA + 32768;
    const char* Bc = rdB + 32768;
    LGKM0();
    RD_B1(Bc);
    PRIO_MFMA(0, 0, a0, b0);
    VMCNT(0); BARRIER();
    LGKM0();
    RD_A1(Ac);
    PRIO_MFMA(0, 1, a0, b1);
    LGKM0();
    PRIO_MFMA(1, 0, a1, b0);
    PRIO_MFMA(1, 1, a1, b1);
  }

  const int er = g * 4, ec = lane & 15;
  if (EPI == 0) {
    unsigned short* C = (unsigned short*)Cout;
    #pragma unroll
    for (int i = 0; i < 8; ++i)
      #pragma unroll
      for (int j = 0; j < 4; ++j) {
        const int gr = m0 + wm*128 + i*16 + er;
        const int gc = n0 + wn*64 + j*16 + ec;
        #pragma unroll
        for (int e = 0; e < 4; ++e)
          C[(size_t)(gr + e) * ldc + gc] = f2bf(acc[i][j][e]);
      }
  } else {
    unsigned short* C = (unsigned short*)Cout;
    #pragma unroll
    for (int i = 0; i < 8; ++i)
      #pragma unroll
      for (int tp = 0; tp < 2; ++tp) {
        const int gr = m0 + wm*128 + i*16 + er;
        const int hc = (n0 >> 1) + wn*32 + tp*16 + ec;
        #pragma unroll
        for (int e = 0; e < 4; ++e) {
          const float gv = acc[i][2*tp][e];
          const float uv = acc[i][2*tp + 1][e];
          const float hv = gv / (1.f + __expf(-gv)) * uv;
          C[(size_t)(gr + e) * ldc + hc] = f2bf(hv);
        }
      }
  }
#undef STG_GA0
#undef STG_GA1
#undef STG_GB0
#undef STG_GB1
#undef MFMA_Q
#undef VMCNT
#undef LGKM0
#undef BARRIER
#undef RD_A0
#undef RD_A1
#undef RD_B0
#undef RD_B1
#undef PRIO_MFMA
}

// ---------------------------------------------------------------------------
// Flash attention (causal), KVBLK=128. grid (T/128, B*H), block 512.
// ---------------------------------------------------------------------------
__global__ __launch_bounds__(512) void attn_fwd(const unsigned short* __restrict__ qkv,
                                                const unsigned short* __restrict__ vt,
                                                unsigned short* __restrict__ outp)
{
  __shared__ __align__(16) unsigned short lK[2][128*64];
  __shared__ __align__(16) unsigned short lV[2][64*128];
  const int nx = gridDim.x;
  const int wsz = xcd_swz_flat();
  const int qblk = wsz % nx;
  const int bh = wsz / nx, b = bh >> 4, h = bh & 15;
  const int tid = threadIdx.x, wid = tid >> 6, lane = tid & 63;
  const int lq = lane & 15, g = lane >> 4;

  const int qrow = qblk*128 + wid*16;
  const int myq = qrow + lq;

  const size_t qbase = ((size_t)(b*TSEQ + myq)) * QKVN + h*HD;
  const s16x8 qf0 = *(const s16x8*)&qkv[qbase + g*8];
  const s16x8 qf1 = *(const s16x8*)&qkv[qbase + 32 + g*8];

  const int pk = tid * 16;
  const int Lk0 = pk ^ (((pk >> 7) & 7) << 4);
  const int Lk1 = (pk + 8192) ^ ((((pk + 8192) >> 7) & 7) << 4);
  const char* ks0 = (const char*)qkv + (((size_t)(b*TSEQ + (Lk0 >> 7))) * QKVN + DIM + h*HD) * 2 + (Lk0 & 127);
  const char* ks1 = (const char*)qkv + (((size_t)(b*TSEQ + (Lk1 >> 7))) * QKVN + DIM + h*HD) * 2 + (Lk1 & 127);
  const int Lv0 = pk ^ (((pk >> 8) & 7) << 4);
  const int Lv1 = (pk + 8192) ^ ((((pk + 8192) >> 8) & 7) << 4);
  const char* vs0 = (const char*)vt + (((size_t)bh*HD + (Lv0 >> 8)) * TSEQ) * 2 + (Lv0 & 255);
  const char* vs1 = (const char*)vt + (((size_t)bh*HD + (Lv1 >> 8)) * TSEQ) * 2 + (Lv1 & 255);

#define STAGE_KV(kt, buf) do { \
    gld16(ks0 + (size_t)(kt)*128*(QKVN*2), (char*)lK[buf] + pk); \
    gld16(ks1 + (size_t)(kt)*128*(QKVN*2), (char*)lK[buf] + pk + 8192); \
    gld16(vs0 + (size_t)(kt)*256,          (char*)lV[buf] + pk); \
    gld16(vs1 + (size_t)(kt)*256,          (char*)lV[buf] + pk + 8192); } while (0)

  float mrun = -INFINITY, lrun = 0.f;
  f32x4 of[4] = {};

  const int nkt = qblk + 1;

  STAGE_KV(0, 0);
  int cur = 0;

  for (int kt = 0; kt < nkt; ++kt) {
    __syncthreads();
    if (kt + 1 < nkt) STAGE_KV(kt + 1, cur ^ 1);
    {
      const char* Kb = (const char*)lK[cur];
      const char* Vb = (const char*)lV[cur];
      f32x4 sacc[8];
      __builtin_amdgcn_s_setprio(1);
      #pragma unroll
      for (int s = 0; s < 8; ++s) {
        const int r = s*16 + lq;
        const int sw = (r & 7) << 4;
        const s16x8 kf0 = *(const s16x8*)(Kb + r*128 + ((g*16) ^ sw));
        const s16x8 kf1 = *(const s16x8*)(Kb + r*128 + ((64 + g*16) ^ sw));
        f32x4 z = {0.f,0.f,0.f,0.f};
        z = __builtin_amdgcn_mfma_f32_16x16x32_bf16(kf0, qf0, z, 0,0,0);
        z = __builtin_amdgcn_mfma_f32_16x16x32_bf16(kf1, qf1, z, 0,0,0);
        sacc[s] = z;
      }
      __builtin_amdgcn_s_setprio(0);
      float p[8][4];
      float mt = -INFINITY;
      #pragma unroll
      for (int s = 0; s < 8; ++s)
        #pragma unroll
        for (int e = 0; e < 4; ++e) {
          const int key = kt*128 + s*16 + 4*g + e;
          const float v = (key <= myq) ? sacc[s][e]*0.125f : -INFINITY;
          p[s][e] = v;
          mt = fmaxf(mt, v);
        }
      mt = fmaxf(mt, __shfl_xor(mt, 16));
      mt = fmaxf(mt, __shfl_xor(mt, 32));
      const float mnew = fmaxf(mrun, mt);
      const float scale = __expf(mrun - mnew);
      float ssum = 0.f;
      #pragma unroll
      for (int s = 0; s < 8; ++s)
        #pragma unroll
        for (int e = 0; e < 4; ++e) {
          p[s][e] = __expf(p[s][e] - mnew);
          ssum += p[s][e];
        }
      ssum += __shfl_xor(ssum, 16);
      ssum += __shfl_xor(ssum, 32);
      lrun = lrun * scale + ssum;
      mrun = mnew;
      #pragma unroll
      for (int d0b = 0; d0b < 4; ++d0b) of[d0b] = of[d0b] * scale;
      #pragma unroll
      for (int hh = 0; hh < 4; ++hh) {
        unsigned w[4];
        #pragma unroll
        for (int j = 0; j < 4; ++j) w[j] = pack_bf2(p[2*hh][j], p[2*hh+1][j]);
        s16x8 bp;
        #pragma unroll
        for (int e = 0; e < 8; ++e) {
          const int srcg = 2*(g & 1) + (e >> 2);
          const unsigned ww = (unsigned)__shfl((int)w[e & 3], lq | (srcg << 4));
          bp[e] = (short)((g >= 2) ? (ww >> 16) : (ww & 0xffffu));
        }
        __builtin_amdgcn_s_setprio(1);
        #pragma unroll
        for (int d0b = 0; d0b < 4; ++d0b) {
          const int r = d0b*16 + lq;
          const int sw = (r & 7) << 4;
          const s16x8 vf = *(const s16x8*)(Vb + r*256 + ((hh*64 + g*16) ^ sw));
          of[d0b] = __builtin_amdgcn_mfma_f32_16x16x32_bf16(vf, bp, of[d0b], 0,0,0);
        }
        __builtin_amdgcn_s_setprio(0);
      }
    }
    cur ^= 1;
  }
  const float inv = 1.f / lrun;
  const size_t obase = ((size_t)(b*TSEQ + myq)) * DIM + h*HD;
  #pragma unroll
  for (int d0b = 0; d0b < 4; ++d0b) {
    ushort4 o;
    o.x = f2bf(of[d0b][0] * inv);
    o.y = f2bf(of[d0b][1] * inv);
    o.z = f2bf(of[d0b][2] * inv);
    o.w = f2bf(of[d0b][3] * inv);
    *(ushort4*)&outp[obase + d0b*16 + 4*g] = o;
  }
#undef STAGE_KV
}

// ---------------------------------------------------------------------------
extern "C" void kernel_launch(void* const* d_in, const int* in_sizes, int n_in,
                              void* d_out, int out_size, void* d_ws, size_t ws_size,
                              hipStream_t stream)
{
  const float* x   = (const float*)d_in[0];
  const float* wq  = (const float*)d_in[1];
  const float* wk  = (const float*)d_in[2];
  const float* wv  = (const float*)d_in[3];
  const float* wo  = (const float*)d_in[4];
  const float* wg  = (const float*)d_in[5];
  const float* wu  = (const float*)d_in[6];
  const float* wd  = (const float*)d_in[7];
  const float* anw = (const float*)d_in[8];
  const float* fnw = (const float*)d_in[9];
  float* outp = (float*)d_out;

  const size_t MB = 1024*1024;
  const size_t RD = (size_t)ROWS * DIM;
  char* ws = (char*)d_ws;
  float*          x1    = (float*)         (ws + 0);
  unsigned short* wdT   = (unsigned short*)(ws + 16*MB);
  unsigned short* wguT  = (unsigned short*)(ws + 24*MB);
  unsigned short* wqkvT = (unsigned short*)(ws + 40*MB);
  unsigned short* woT   = (unsigned short*)(ws + 46*MB);
  unsigned short* xn    = (unsigned short*)(ws + 48*MB);
  unsigned short* qkv   = (unsigned short*)(ws + 56*MB);
  unsigned short* vtb   = (unsigned short*)(ws + 80*MB);
  unsigned short* aout  = (unsigned short*)(ws + 88*MB);
  unsigned short* pwo   = (unsigned short*)(ws + 56*MB);   // 2 x 8MB bf16 WO partials
  unsigned short* hbuf  = (unsigned short*)(ws + 56*MB);   // 32MB
  unsigned short* pdn   = (unsigned short*)(ws + 24*MB);   // 4 x 8MB bf16 down partials

  const dim3 blk(256);

  // prologue: all weight transposes + attn rmsnorm in ONE launch
  prologue_k<<<dim3(8192), blk, 0, stream>>>(wq, wk, wv, wo, wg, wu, wd,
                                             wqkvT, woT, wguT, wdT,
                                             x, anw, xn);

  // attention path (V-transpose fused into QKV epilogue)
  gemm128sp<1,2><<<dim3(QKVN/128, ROWS/128, 1), blk, 0, stream>>>(xn, DIM, wqkvT, DIM, qkv, QKVN, DIM, vtb);
  attn_fwd<<<dim3(TSEQ/128, BATCH*NH), dim3(512), 0, stream>>>(qkv, vtb, aout);
  gemm128sp<2,0><<<dim3(DIM/128, ROWS/128, 2), blk, 0, stream>>>(aout, DIM, woT, DIM, pwo, DIM, DIM/2, nullptr);
  rmsnorm3_k<<<ROWS, blk, 0, stream>>>(x, pwo, pwo + RD, fnw, x1, xn);

  // ffn path: gate/up on gemm256 with fused silu epilogue (best measured)
  gemm256<2><<<dim3(2*FFN/256, ROWS/256), dim3(512), 0, stream>>>(xn, DIM, wguT, DIM, hbuf, FFN, DIM, 4, 2);
  gemm128sp<4,0><<<dim3(DIM/128, ROWS/128, 4), blk, 0, stream>>>(hbuf, FFN, wdT, FFN, pdn, DIM, FFN/4, nullptr);
  resadd5_k<<<dim3(ROWS*DIM/1024), blk, 0, stream>>>(x1, pdn, pdn + RD, pdn + 2*RD, pdn + 3*RD, outp);
}